// Round 1
// baseline (264.646 us; speedup 1.0000x reference)
//
#include <hip/hip_runtime.h>

#define NB 32768

typedef _Float16 half8 __attribute__((ext_vector_type(8)));
typedef float floatx4 __attribute__((ext_vector_type(4)));
typedef unsigned int uint4v __attribute__((ext_vector_type(4)));

#define MFMA16(a,b,c) __builtin_amdgcn_mfma_f32_16x16x32_f16(a,b,c,0,0,0)

// ---------- fast math ----------
__device__ __forceinline__ float rcp_f(float x){ return __builtin_amdgcn_rcpf(x); }
__device__ __forceinline__ float exp2_f(float x){ return __builtin_amdgcn_exp2f(x); }
__device__ __forceinline__ float tanh_f(float x){
  float e = exp2_f(x * 2.8853900817779268f);     // e^(2x)
  return (e - 1.0f) * rcp_f(e + 1.0f);
}
__device__ __forceinline__ float sigmoid_f(float x){
  return rcp_f(1.0f + exp2_f(-1.4426950408889634f * x));
}

// DPP butterflies within an 8-lane group:
// xor1 = quad_perm[1,0,3,2]=0xB1, xor2 = quad_perm[2,3,0,1]=0x4E,
// cross-quad = row_half_mirror (0x141): lane i -> 7-i within each 8-lane half.
template<int CTRL>
__device__ __forceinline__ float dpp_qp(float x){
  return __builtin_bit_cast(float, __builtin_amdgcn_update_dpp(0, __builtin_bit_cast(int,x), CTRL, 0xF, 0xF, true));
}
__device__ __forceinline__ float qadd3(float x){
  x += dpp_qp<0xB1>(x);
  x += dpp_qp<0x4E>(x);
  x += dpp_qp<0x141>(x);
  return x;
}
__device__ __forceinline__ float qmax3(float x){
  x = fmaxf(x, dpp_qp<0xB1>(x));
  x = fmaxf(x, dpp_qp<0x4E>(x));
  x = fmaxf(x, dpp_qp<0x141>(x));
  return x;
}

// ---------- f16 weight region offsets (in _Float16 units), lives in d_ws ----------
constexpr int O_AW0H = 0;        // 256x128
constexpr int O_AW1H = 32768;    // 128x128
constexpr int O_AW2H = 49152;
constexpr int O_AW3H = 65536;    // 128x256
constexpr int O_PW0H = 98304;
constexpr int O_PW1H = 131072;
constexpr int O_PW2H = 147456;
constexpr int O_PW3H = 163840;   // 128x16
constexpr int O_AW1L = 165888;
constexpr int O_AW2L = 182272;
constexpr int O_AW3L = 198656;

// ---------- weight prep: transpose + split f32 -> f16 hi/lo ----------
struct PrepJob { const float* src; _Float16* h; _Float16* l; int kshift; int total; };
struct PrepJobs { PrepJob j[8]; };

__global__ void prep_kernel(PrepJobs js){
  const PrepJob jb = js.j[blockIdx.y];
  const int idx = blockIdx.x*256 + threadIdx.x;
  if (idx >= jb.total) return;
  const int K = 1 << jb.kshift;
  const int n = idx >> jb.kshift;
  const int k = idx & (K-1);
  const int N = jb.total >> jb.kshift;
  float w = jb.src[(long)k*N + n];
  _Float16 h = (_Float16)w;
  jb.h[idx] = h;
  if (jb.l) jb.l[idx] = (_Float16)(w - (float)h);
}

// ---------- LDS activation layout: 16 rows x 128 cols of packed (hi|lo) u32 ----------
// 16B-chunk XOR swizzle by (row&7)
__device__ __forceinline__ int aaddr(int row, int col){
  int cc = (col >> 2) ^ (row & 7);
  return row*128 + (cc<<2) + (col & 3);
}

template<bool NEED_LO>
__device__ __forceinline__ void read_frag(const unsigned int* __restrict__ act,
    int row, int ks, int q, half8& ah, half8& al)
{
  const int s = row & 7;
  const int cc0 = ks*8 + q*2;
  uint4v c0 = *(const uint4v*)(act + row*128 + (((cc0  ) ^ s)<<2));
  uint4v c1 = *(const uint4v*)(act + row*128 + (((cc0+1) ^ s)<<2));
  uint4v h;
  h.x = (c0.x & 0xffffu) | (c0.y << 16);
  h.y = (c0.z & 0xffffu) | (c0.w << 16);
  h.z = (c1.x & 0xffffu) | (c1.y << 16);
  h.w = (c1.z & 0xffffu) | (c1.w << 16);
  ah = __builtin_bit_cast(half8, h);
  if constexpr (NEED_LO){
    uint4v g;
    g.x = (c0.x >> 16) | (c0.y & 0xffff0000u);
    g.y = (c0.z >> 16) | (c0.w & 0xffff0000u);
    g.z = (c1.x >> 16) | (c1.y & 0xffff0000u);
    g.w = (c1.z >> 16) | (c1.w & 0xffff0000u);
    al = __builtin_bit_cast(half8, g);
  }
}

__device__ __forceinline__ unsigned int pack_act(float v){
  _Float16 h = (_Float16)v;
  _Float16 lo = (_Float16)(v - (float)h);
  return (unsigned int)__builtin_bit_cast(unsigned short, h)
       | ((unsigned int)__builtin_bit_cast(unsigned short, lo) << 16);
}

__device__ __forceinline__ half8 load_xfrag(const float* __restrict__ X, long row, int k0){
  float4 a = *(const float4*)(X + row*256 + k0);
  float4 b = *(const float4*)(X + row*256 + k0 + 4);
  half8 h;
  h[0]=(_Float16)a.x; h[1]=(_Float16)a.y; h[2]=(_Float16)a.z; h[3]=(_Float16)a.w;
  h[4]=(_Float16)b.x; h[5]=(_Float16)b.y; h[6]=(_Float16)b.z; h[7]=(_Float16)b.w;
  return h;
}

// ---------- MFMA inner block: 1 m-tile x NT n-tiles starting at nt0, K = KS*32 ----------
template<int KS, int PASSES, int NT>
__device__ __forceinline__ void mfma_block(
    const half8* Ah, const half8* Al,
    const _Float16* __restrict__ Wh, const _Float16* __restrict__ Wl,
    int K, int nt0, int l15, int q, floatx4* acc)
{
#pragma unroll
  for (int nt=0; nt<NT; ++nt){
    const _Float16* bp = Wh + ((nt0+nt)*16 + l15)*K + q*8;
#pragma unroll
    for (int ks=0; ks<KS; ++ks){
      half8 bh = *(const half8*)(bp + ks*32);
      acc[nt] = MFMA16(Ah[ks], bh, acc[nt]);
      if constexpr (PASSES == 3){
        const _Float16* blp = Wl + ((nt0+nt)*16 + l15)*K + q*8;
        half8 bl = *(const half8*)(blp + ks*32);
        acc[nt] = MFMA16(Al[ks], bh, acc[nt]);
        acc[nt] = MFMA16(Ah[ks], bl, acc[nt]);
      }
    }
  }
}

// epilogue: bias+tanh+pack to LDS; rows q*4 + r, cols (nt0+nt)*16 + l15
template<int NT>
__device__ __forceinline__ void epi_tanh(floatx4* acc, const float* __restrict__ bias,
    unsigned int* __restrict__ act, int nt0, int q, int l15)
{
#pragma unroll
  for (int nt=0; nt<NT; ++nt){
    float bb = bias[(nt0+nt)*16 + l15];
#pragma unroll
    for (int r=0; r<4; ++r){
      float t = tanh_f(acc[nt][r] + bb);
      act[aaddr(q*4 + r, (nt0+nt)*16 + l15)] = pack_act(t);
    }
  }
}

// one hidden stage: a-layer (3-pass hi/lo) + p-layer (1-pass), column-split by wave.
// Pattern: read all frags -> barrier -> compute+write -> barrier (read/write same buffer
// across 2 waves requires both barriers).
__device__ __forceinline__ void stage_h(unsigned int* __restrict__ act_a,
    unsigned int* __restrict__ act_p,
    const _Float16* __restrict__ Wah, const _Float16* __restrict__ Wal, const float* __restrict__ ba,
    const _Float16* __restrict__ Wph, const float* __restrict__ bpp,
    int nt0, int q, int l15)
{
  half8 Aah[4], Aal[4], Aph[4], du;
#pragma unroll
  for (int ks=0; ks<4; ++ks) read_frag<true >(act_a, l15, ks, q, Aah[ks], Aal[ks]);
#pragma unroll
  for (int ks=0; ks<4; ++ks) read_frag<false>(act_p, l15, ks, q, Aph[ks], du);
  __syncthreads();
  floatx4 acca[4], accp[4];
#pragma unroll
  for (int nt=0; nt<4; ++nt){ acca[nt] = (floatx4)0.0f; accp[nt] = (floatx4)0.0f; }
  mfma_block<4,3,4>(Aah, Aal, Wah, Wal, 128, nt0, l15, q, acca);
  epi_tanh<4>(acca, ba, act_a, nt0, q, l15);
  mfma_block<4,1,4>(Aph, Aph, Wph, Wph, 128, nt0, l15, q, accp);
  epi_tanh<4>(accp, bpp, act_p, nt0, q, l15);
  __syncthreads();
}

// ================= Fused kernel: MLPs + Sinkhorn + payments =================
// 128 threads = 2 waves per block, 16 rows/block. Column-split MLP (wave w owns output
// cols w*64..w*64+63 of every 128-wide layer; a-L4 half hf=w; p-L4 on wave0).
// Sinkhorn: 8 lanes per element (2 cols/lane), 3-level DPP butterfly reduce.
// LDS map: S[0..2048) = act_a (u32 hi|lo), S[2048..4096) = act_p,
//          S[0..4096) REUSED as aug f32 (16 rows x 256) after act pre-reads.
//          S[4096..4352) = frac f32.
// 2048 blocks x 2 waves = 4096 waves -> 16 waves/CU (LDS 8x17408B = 139KB/CU).
__global__ __launch_bounds__(128, 4) void fused_kernel(
  const float* __restrict__ X, const _Float16* __restrict__ WT,
  const float* __restrict__ ab0, const float* __restrict__ ab1,
  const float* __restrict__ ab2, const float* __restrict__ ab3,
  const float* __restrict__ pb0, const float* __restrict__ pb1,
  const float* __restrict__ pb2, const float* __restrict__ pb3,
  float* __restrict__ out)
{
  __shared__ unsigned int S[16*256 + 256];   // 17408 B
  unsigned int* act_a = S;
  unsigned int* act_p = S + 2048;
  float* frac_l = (float*)(S + 4096);
  const int t = threadIdx.x;
  const int w = t >> 6;                      // wave id 0/1
  const int l = t & 63, q = l>>4, l15 = l&15;
  const int nt0 = w*4;                       // this wave's n-tile base (cols w*64..)
  const long rb = (long)blockIdx.x * 16;

  // ---- L1 of both nets from one X fragment set (K=256), 4 n-tiles per wave ----
  {
    half8 Xf[8];
#pragma unroll
    for (int ks=0; ks<8; ++ks)
      Xf[ks] = load_xfrag(X, rb + l15, ks*32 + q*8);
    floatx4 acca[4], accp[4];
#pragma unroll
    for (int nt=0; nt<4; ++nt){ acca[nt] = (floatx4)0.0f; accp[nt] = (floatx4)0.0f; }
    mfma_block<8,1,4>(Xf, Xf, WT+O_AW0H, WT+O_AW0H, 256, nt0, l15, q, acca);
    mfma_block<8,1,4>(Xf, Xf, WT+O_PW0H, WT+O_PW0H, 256, nt0, l15, q, accp);
    epi_tanh<4>(acca, ab0, act_a, nt0, q, l15);
    epi_tanh<4>(accp, pb0, act_p, nt0, q, l15);
  }
  __syncthreads();

  // ---- hidden layers, column-split ----
  stage_h(act_a, act_p, WT+O_AW1H, WT+O_AW1L, ab1, WT+O_PW1H, pb1, nt0, q, l15);
  stage_h(act_a, act_p, WT+O_AW2H, WT+O_AW2L, ab2, WT+O_PW2H, pb2, nt0, q, l15);

  // ---- L4: pre-read all act frags, barrier, then p-L4 (wave0) + aug halves ----
  {
    half8 Aah[4], Aal[4], Aph[4], du;
#pragma unroll
    for (int ks=0; ks<4; ++ks) read_frag<true>(act_a, l15, ks, q, Aah[ks], Aal[ks]);
    if (w == 0){
#pragma unroll
      for (int ks=0; ks<4; ++ks) read_frag<false>(act_p, l15, ks, q, Aph[ks], du);
    }
    __syncthreads();
    if (w == 0){
      floatx4 acc1 = (floatx4)0.0f;
      mfma_block<4,1,1>(Aph, Aph, WT+O_PW3H, WT+O_PW3H, 128, 0, l15, q, &acc1);
      float bb = pb3[l15];
#pragma unroll
      for (int r=0; r<4; ++r)
        frac_l[(q*4+r)*16 + l15] = sigmoid_f(acc1[r] + bb);
    }
    // aug half hf = w (cols w*128 .. w*128+127), overlays act_a/act_p (all reads done)
    float* augl = (float*)S;
    floatx4 acc[8];
#pragma unroll
    for (int nt=0; nt<8; ++nt) acc[nt] = (floatx4)0.0f;
    mfma_block<4,3,8>(Aah, Aal, WT+O_AW3H + w*128*128, WT+O_AW3L + w*128*128, 128, 0, l15, q, acc);
    const int ncol0 = w*128;
#pragma unroll
    for (int nt=0; nt<8; ++nt){
      float bb = ab3[ncol0 + nt*16 + l15];
#pragma unroll
      for (int r=0; r<4; ++r)
        augl[(q*4+r)*256 + ncol0 + nt*16 + l15] = acc[nt][r] + bb;
    }
    __syncthreads();
  }

  // ================= Sinkhorn + payments: 8 lanes per element =================
  const int cp = t & 7;                  // lane within element group; owns cols 2cp, 2cp+1
  const int eL = t >> 3;                 // local element 0..15
  const long e = rb + eL;                // global element
  const float Ssc = 14.426950408889634f; // (1/EPS)/ln2 : logits in exp2 units
  const float cmask = (cp == 7) ? 1.0f : 0.0f;

  float Kx[2][17];   // owned columns (2cp, 2cp+1), rows 0..16 (row 16 = pad row)
  float K16[17];     // pad column 16 (lane 7 only; zeroed elsewhere)

  const float* ap = (const float*)S + eL*256 + 2*cp;
#pragma unroll
  for (int i=0;i<16;++i){
    float2 v = *(const float2*)(ap + i*16);
    Kx[0][i]=v.x*Ssc; Kx[1][i]=v.y*Ssc;
  }
  Kx[0][16]=0.f; Kx[1][16]=0.f;

  float u[17];
#pragma unroll
  for (int i=0;i<17;++i){
    float mm = fmaxf(fmaxf(Kx[0][i],Kx[1][i]), 0.0f);
    mm = qmax3(mm);
    Kx[0][i] = exp2_f(Kx[0][i]-mm);
    Kx[1][i] = exp2_f(Kx[1][i]-mm);
    K16[i]   = cmask * exp2_f(-mm);
  }

  float vj0=1.f, vj1=1.f;
  float v16 = cmask;

  for (int r=0;r<40;++r){
#pragma unroll
    for (int i=0;i<17;++i){
      float p = Kx[0][i]*vj0 + Kx[1][i]*vj1 + K16[i]*v16;
      p = qadd3(p);
      u[i] = rcp_f(p);
    }
    u[16] *= 16.0f;   // a_16 = I = 16
    float t0=0.f,t1=0.f,t16=0.f;
#pragma unroll
    for (int i=0;i<17;++i){
      t0  = fmaf(Kx[0][i],u[i],t0);
      t1  = fmaf(Kx[1][i],u[i],t1);
      t16 = fmaf(K16[i], u[i],t16);
    }
    vj0 = rcp_f(t0); vj1 = rcp_f(t1);
    v16 = cmask * 16.0f * rcp_f(t16 + 1e-30f + (1.0f - cmask));  // b_16 = A = 16; NaN-guard off-lane
  }

  // allocs = u_i * K_ij * v_j  (real 16x16 block), float2 per lane per row
  float* op = out + e*256 + 2*cp;
#pragma unroll
  for (int i=0;i<16;++i){
    float2 wv;
    wv.x = u[i]*Kx[0][i]*vj0;
    wv.y = u[i]*Kx[1][i]*vj1;
    *(float2*)(op + i*16) = wv;
  }

  // payments_i = frac_i * sum_j allocs_ij * bids_ij (bids re-read, L1/L3-hot).
  // After the butterfly every lane holds pay[i]; keep only this lane's two cols
  // via compile-time-i predicated assigns (no runtime-indexed array -> no scratch).
  const float* bpx = X + e*256 + 2*cp;
  float p0 = 0.f, p1 = 0.f;
#pragma unroll
  for (int i=0;i<16;++i){
    float2 bb = *(const float2*)(bpx + i*16);
    float s = u[i]*(Kx[0][i]*vj0*bb.x + Kx[1][i]*vj1*bb.y);
    s = qadd3(s);
    if ((i>>1) == cp){ if (i&1) p1 = s; else p0 = s; }
  }
  const float2 fr = *(const float2*)(frac_l + eL*16 + 2*cp);
  float2 pv; pv.x = p0*fr.x; pv.y = p1*fr.y;
  *(float2*)(out + (size_t)NB*256 + e*16 + 2*cp) = pv;
}

// ================= launch =================
extern "C" void kernel_launch(void* const* d_in, const int* in_sizes, int n_in,
                              void* d_out, int out_size, void* d_ws, size_t ws_size,
                              hipStream_t stream)
{
  const float* bids = (const float*)d_in[0];
  const float* aw0 = (const float*)d_in[1];  const float* ab0 = (const float*)d_in[2];
  const float* aw1 = (const float*)d_in[3];  const float* ab1 = (const float*)d_in[4];
  const float* aw2 = (const float*)d_in[5];  const float* ab2 = (const float*)d_in[6];
  const float* aw3 = (const float*)d_in[7];  const float* ab3 = (const float*)d_in[8];
  const float* pw0 = (const float*)d_in[9];  const float* pb0 = (const float*)d_in[10];
  const float* pw1 = (const float*)d_in[11]; const float* pb1 = (const float*)d_in[12];
  const float* pw2 = (const float*)d_in[13]; const float* pb2 = (const float*)d_in[14];
  const float* pw3 = (const float*)d_in[15]; const float* pb3 = (const float*)d_in[16];

  _Float16* WT = (_Float16*)d_ws;

  PrepJobs js;
  js.j[0] = { aw0, WT+O_AW0H, nullptr,    8, 32768 };
  js.j[1] = { aw1, WT+O_AW1H, WT+O_AW1L,  7, 16384 };
  js.j[2] = { aw2, WT+O_AW2H, WT+O_AW2L,  7, 16384 };
  js.j[3] = { aw3, WT+O_AW3H, WT+O_AW3L,  7, 32768 };
  js.j[4] = { pw0, WT+O_PW0H, nullptr,    8, 32768 };
  js.j[5] = { pw1, WT+O_PW1H, nullptr,    7, 16384 };
  js.j[6] = { pw2, WT+O_PW2H, nullptr,    7, 16384 };
  js.j[7] = { pw3, WT+O_PW3H, nullptr,    7, 2048  };

  prep_kernel<<<dim3(128,8), 256, 0, stream>>>(js);
  fused_kernel<<<dim3(NB/16), 128, 0, stream>>>(bids, WT, ab0,ab1,ab2,ab3,
                                                pb0,pb1,pb2,pb3, (float*)d_out);
}

// Round 2
// 254.918 us; speedup vs baseline: 1.0382x; 1.0382x over previous
//
#include <hip/hip_runtime.h>

#define NB 32768

typedef _Float16 half8 __attribute__((ext_vector_type(8)));
typedef float floatx4 __attribute__((ext_vector_type(4)));
typedef float floatx2 __attribute__((ext_vector_type(2)));
typedef unsigned int uint4v __attribute__((ext_vector_type(4)));

#define MFMA16(a,b,c) __builtin_amdgcn_mfma_f32_16x16x32_f16(a,b,c,0,0,0)

// ---------- fast math ----------
__device__ __forceinline__ float rcp_f(float x){ return __builtin_amdgcn_rcpf(x); }
__device__ __forceinline__ float exp2_f(float x){ return __builtin_amdgcn_exp2f(x); }
__device__ __forceinline__ float tanh_f(float x){
  float e = exp2_f(x * 2.8853900817779268f);     // e^(2x)
  return (e - 1.0f) * rcp_f(e + 1.0f);
}
__device__ __forceinline__ float sigmoid_f(float x){
  return rcp_f(1.0f + exp2_f(-1.4426950408889634f * x));
}

// packed f32 math (VOP3P) — halves fma/mul issue count in Sinkhorn
__device__ __forceinline__ floatx2 pk_mul2(floatx2 a, floatx2 b){
  floatx2 d; asm("v_pk_mul_f32 %0, %1, %2" : "=v"(d) : "v"(a), "v"(b)); return d;
}
__device__ __forceinline__ floatx2 pk_fma2(floatx2 a, floatx2 b, floatx2 c){
  floatx2 d; asm("v_pk_fma_f32 %0, %1, %2, %3" : "=v"(d) : "v"(a), "v"(b), "v"(c)); return d;
}

// DPP quad butterflies: xor1 = quad_perm[1,0,3,2]=0xB1, xor2 = [2,3,0,1]=0x4E
template<int CTRL>
__device__ __forceinline__ float dpp_qp(float x){
  return __builtin_bit_cast(float, __builtin_amdgcn_update_dpp(0, __builtin_bit_cast(int,x), CTRL, 0xF, 0xF, true));
}
__device__ __forceinline__ float qadd2(float x){
  x += dpp_qp<0xB1>(x);
  x += dpp_qp<0x4E>(x);
  return x;
}
__device__ __forceinline__ float qmax2(float x){
  x = fmaxf(x, dpp_qp<0xB1>(x));
  x = fmaxf(x, dpp_qp<0x4E>(x));
  return x;
}

// ---------- f16 weight region offsets (in _Float16 units), lives in d_ws ----------
constexpr int O_AW0H = 0;        // 256x128
constexpr int O_AW1H = 32768;    // 128x128
constexpr int O_AW2H = 49152;
constexpr int O_AW3H = 65536;    // 128x256
constexpr int O_PW0H = 98304;
constexpr int O_PW1H = 131072;
constexpr int O_PW2H = 147456;
constexpr int O_PW3H = 163840;   // 128x16
constexpr int O_AW1L = 165888;
constexpr int O_AW2L = 182272;
constexpr int O_AW3L = 198656;

// ---------- weight prep: transpose + split f32 -> f16 hi/lo ----------
struct PrepJob { const float* src; _Float16* h; _Float16* l; int kshift; int total; };
struct PrepJobs { PrepJob j[8]; };

__global__ void prep_kernel(PrepJobs js){
  const PrepJob jb = js.j[blockIdx.y];
  const int idx = blockIdx.x*256 + threadIdx.x;
  if (idx >= jb.total) return;
  const int K = 1 << jb.kshift;
  const int n = idx >> jb.kshift;
  const int k = idx & (K-1);
  const int N = jb.total >> jb.kshift;
  float w = jb.src[(long)k*N + n];
  _Float16 h = (_Float16)w;
  jb.h[idx] = h;
  if (jb.l) jb.l[idx] = (_Float16)(w - (float)h);
}

// ---------- LDS activation layout: 16 rows x 128 cols of packed (hi|lo) u32 ----------
// 16B-chunk XOR swizzle by (row&7)
__device__ __forceinline__ int aaddr(int row, int col){
  int cc = (col >> 2) ^ (row & 7);
  return row*128 + (cc<<2) + (col & 3);
}

template<bool NEED_LO>
__device__ __forceinline__ void read_frag(const unsigned int* __restrict__ act,
    int row, int ks, int q, half8& ah, half8& al)
{
  const int s = row & 7;
  const int cc0 = ks*8 + q*2;
  uint4v c0 = *(const uint4v*)(act + row*128 + (((cc0  ) ^ s)<<2));
  uint4v c1 = *(const uint4v*)(act + row*128 + (((cc0+1) ^ s)<<2));
  uint4v h;
  h.x = (c0.x & 0xffffu) | (c0.y << 16);
  h.y = (c0.z & 0xffffu) | (c0.w << 16);
  h.z = (c1.x & 0xffffu) | (c1.y << 16);
  h.w = (c1.z & 0xffffu) | (c1.w << 16);
  ah = __builtin_bit_cast(half8, h);
  if constexpr (NEED_LO){
    uint4v g;
    g.x = (c0.x >> 16) | (c0.y & 0xffff0000u);
    g.y = (c0.z >> 16) | (c0.w & 0xffff0000u);
    g.z = (c1.x >> 16) | (c1.y & 0xffff0000u);
    g.w = (c1.z >> 16) | (c1.w & 0xffff0000u);
    al = __builtin_bit_cast(half8, g);
  }
}

__device__ __forceinline__ unsigned int pack_act(float v){
  _Float16 h = (_Float16)v;
  _Float16 lo = (_Float16)(v - (float)h);
  return (unsigned int)__builtin_bit_cast(unsigned short, h)
       | ((unsigned int)__builtin_bit_cast(unsigned short, lo) << 16);
}
// p-net never reads the lo half -> hi-only pack (saves ~3 VALU ops/value)
__device__ __forceinline__ unsigned int pack_act_hi(float v){
  return (unsigned int)__builtin_bit_cast(unsigned short, (_Float16)v);
}

__device__ __forceinline__ half8 load_xfrag(const float* __restrict__ X, long row, int k0){
  float4 a = *(const float4*)(X + row*256 + k0);
  float4 b = *(const float4*)(X + row*256 + k0 + 4);
  half8 h;
  h[0]=(_Float16)a.x; h[1]=(_Float16)a.y; h[2]=(_Float16)a.z; h[3]=(_Float16)a.w;
  h[4]=(_Float16)b.x; h[5]=(_Float16)b.y; h[6]=(_Float16)b.z; h[7]=(_Float16)b.w;
  return h;
}

// ---------- MFMA inner block: 1 m-tile x NT n-tiles, K = KS*32 ----------
template<int KS, int PASSES, int NT>
__device__ __forceinline__ void mfma_block(
    const half8* Ah, const half8* Al,
    const _Float16* __restrict__ Wh, const _Float16* __restrict__ Wl,
    int K, int l15, int q, floatx4* acc)
{
#pragma unroll
  for (int nt=0; nt<NT; ++nt){
    const _Float16* bp = Wh + (nt*16 + l15)*K + q*8;
#pragma unroll
    for (int ks=0; ks<KS; ++ks){
      half8 bh = *(const half8*)(bp + ks*32);
      acc[nt] = MFMA16(Ah[ks], bh, acc[nt]);
      if constexpr (PASSES == 3){
        const _Float16* blp = Wl + (nt*16 + l15)*K + q*8;
        half8 bl = *(const half8*)(blp + ks*32);
        acc[nt] = MFMA16(Al[ks], bh, acc[nt]);
        acc[nt] = MFMA16(Ah[ks], bl, acc[nt]);
      }
    }
  }
}

// epilogue: bias+tanh+pack to LDS; rows q*4 + r
template<bool LO>
__device__ __forceinline__ void epi_tanh(floatx4* acc, const float* __restrict__ bias,
    unsigned int* __restrict__ act, int q, int l15)
{
#pragma unroll
  for (int nt=0; nt<8; ++nt){
    float bb = bias[nt*16 + l15];
#pragma unroll
    for (int r=0; r<4; ++r){
      float t = tanh_f(acc[nt][r] + bb);
      act[aaddr(q*4 + r, nt*16 + l15)] = LO ? pack_act(t) : pack_act_hi(t);
    }
  }
}

template<int PASSES>
__device__ __forceinline__ void hidden128(unsigned int* __restrict__ act,
    const _Float16* __restrict__ Wh, const _Float16* __restrict__ Wl,
    const float* __restrict__ bias, int q, int l15)
{
  half8 Ah[4], Al[4];
#pragma unroll
  for (int ks=0; ks<4; ++ks)
    read_frag<PASSES==3>(act, l15, ks, q, Ah[ks], Al[ks]);
  floatx4 acc[8];
#pragma unroll
  for (int nt=0; nt<8; ++nt) acc[nt] = (floatx4)0.0f;
  mfma_block<4,PASSES,8>(Ah, Al, Wh, Wl, 128, l15, q, acc);
  epi_tanh<PASSES==3>(acc, bias, act, q, l15);
}

// ================= Fused kernel: MLPs + Sinkhorn + payments =================
// 64 threads = 1 wave per block, 16 rows/block. Zero barriers (all LDS traffic is
// wave-local; LDS ops execute in issue order within a wave).
// LDS map: S[0..2048) = act_a (u32 hi|lo), S[2048..4096) = act_p,
//          S[0..4096) REUSED as aug f32 (16 rows x 256) after pL4 (act_p dead) and
//          after aL4 pre-loads act_a into registers. S[4096..4352) = frac f32.
__global__ __launch_bounds__(64, 2) void fused_kernel(
  const float* __restrict__ X, const _Float16* __restrict__ WT,
  const float* __restrict__ ab0, const float* __restrict__ ab1,
  const float* __restrict__ ab2, const float* __restrict__ ab3,
  const float* __restrict__ pb0, const float* __restrict__ pb1,
  const float* __restrict__ pb2, const float* __restrict__ pb3,
  float* __restrict__ out)
{
  __shared__ unsigned int S[16*256 + 256];   // 17408 B
  unsigned int* act_a = S;
  unsigned int* act_p = S + 2048;
  float* frac_l = (float*)(S + 4096);
  const int l = threadIdx.x, q = l>>4, l15 = l&15;
  const long rb = (long)blockIdx.x * 16;

  // ---- L1 of both nets from one X fragment set (K=256) ----
  {
    half8 Xf[8];
#pragma unroll
    for (int ks=0; ks<8; ++ks)
      Xf[ks] = load_xfrag(X, rb + l15, ks*32 + q*8);
    floatx4 acca[8], accp[8];
#pragma unroll
    for (int nt=0; nt<8; ++nt){ acca[nt] = (floatx4)0.0f; accp[nt] = (floatx4)0.0f; }
    mfma_block<8,1,8>(Xf, Xf, WT+O_AW0H, WT+O_AW0H, 256, l15, q, acca);
    mfma_block<8,1,8>(Xf, Xf, WT+O_PW0H, WT+O_PW0H, 256, l15, q, accp);
    epi_tanh<true >(acca, ab0, act_a, q, l15);
    epi_tanh<false>(accp, pb0, act_p, q, l15);
  }
  // ---- hidden layers interleaved: a (3-pass split-corrected), p (1-pass) ----
  hidden128<3>(act_a, WT+O_AW1H, WT+O_AW1L, ab1, q, l15);
  hidden128<1>(act_p, WT+O_PW1H, WT+O_PW1H, pb1, q, l15);
  hidden128<3>(act_a, WT+O_AW2H, WT+O_AW2L, ab2, q, l15);
  hidden128<1>(act_p, WT+O_PW2H, WT+O_PW2H, pb2, q, l15);

  // ---- p-net L4 -> frac (sigmoid) to LDS — MUST precede aL4's aug overlay ----
  {
    half8 Ah[4], Al[4];
#pragma unroll
    for (int ks=0; ks<4; ++ks)
      read_frag<false>(act_p, l15, ks, q, Ah[ks], Al[ks]);
    floatx4 acc1 = (floatx4)0.0f;
    mfma_block<4,1,1>(Ah, Ah, WT+O_PW3H, WT+O_PW3H, 128, l15, q, &acc1);
    float bb = pb3[l15];
#pragma unroll
    for (int r=0; r<4; ++r)
      frac_l[(q*4+r)*16 + l15] = sigmoid_f(acc1[r] + bb);
  }
  // ---- a-net L4 -> aug (f32) into LDS overlay; act_a fully pre-read to regs ----
  {
    half8 Ah[4], Al[4];
#pragma unroll
    for (int ks=0; ks<4; ++ks)
      read_frag<true>(act_a, l15, ks, q, Ah[ks], Al[ks]);
    float* augl = (float*)S;
#pragma unroll
    for (int hf=0; hf<2; ++hf){
      floatx4 acc[8];
#pragma unroll
      for (int nt=0; nt<8; ++nt) acc[nt] = (floatx4)0.0f;
      mfma_block<4,3,8>(Ah, Al, WT+O_AW3H + hf*128*128, WT+O_AW3L + hf*128*128, 128, l15, q, acc);
      const int ncol0 = hf*128;
#pragma unroll
      for (int nt=0; nt<8; ++nt){
        float bb = ab3[ncol0 + nt*16 + l15];
#pragma unroll
        for (int r=0; r<4; ++r)
          augl[(q*4+r)*256 + ncol0 + nt*16 + l15] = acc[nt][r] + bb;
      }
    }
  }

  // ================= Sinkhorn + payments (wave-local, pk-f32 packed) =================
  // Lane owns 4 columns (4c..4c+3). K stored row-PAIR-packed (floatx2 over i).
  // Row 16 of the padded matrix has all-zero logits -> after max-subtract its K
  // entries are exactly 1 (pad col: cmask) -> constant-folded scalar path.
  const int c = l & 3;
  const int eL = l >> 2;                 // local element 0..15
  const long e = rb + eL;                // global element
  const float Ssc = 14.426950408889634f; // (1/EPS)/ln2 : logits in exp2 units
  const float cmask = (c == 3) ? 1.0f : 0.0f;

  floatx2 Kp[4][8];   // owned columns, rows (2k, 2k+1)
  floatx2 KPp[8];     // pad column 16 (lane 3 only; zero elsewhere), row-pairs

  const float* ap = (const float*)S + eL*256 + 4*c;
#pragma unroll
  for (int k=0;k<8;++k){
    float4 va = *(const float4*)(ap + (2*k  )*16);
    float4 vb = *(const float4*)(ap + (2*k+1)*16);
    Kp[0][k] = (floatx2){va.x*Ssc, vb.x*Ssc};
    Kp[1][k] = (floatx2){va.y*Ssc, vb.y*Ssc};
    Kp[2][k] = (floatx2){va.z*Ssc, vb.z*Ssc};
    Kp[3][k] = (floatx2){va.w*Ssc, vb.w*Ssc};
  }

  // max-subtract + exponentiate (row-wise, across the 4 lanes + pad col 0)
#pragma unroll
  for (int k=0;k<8;++k){
    float m0 = fmaxf(fmaxf(Kp[0][k].x,Kp[1][k].x), fmaxf(Kp[2][k].x,Kp[3][k].x));
    m0 = qmax2(fmaxf(m0, 0.0f));
    float m1 = fmaxf(fmaxf(Kp[0][k].y,Kp[1][k].y), fmaxf(Kp[2][k].y,Kp[3][k].y));
    m1 = qmax2(fmaxf(m1, 0.0f));
    Kp[0][k] = (floatx2){exp2_f(Kp[0][k].x-m0), exp2_f(Kp[0][k].y-m1)};
    Kp[1][k] = (floatx2){exp2_f(Kp[1][k].x-m0), exp2_f(Kp[1][k].y-m1)};
    Kp[2][k] = (floatx2){exp2_f(Kp[2][k].x-m0), exp2_f(Kp[2][k].y-m1)};
    Kp[3][k] = (floatx2){exp2_f(Kp[3][k].x-m0), exp2_f(Kp[3][k].y-m1)};
    KPp[k]   = (floatx2){cmask*exp2_f(-m0), cmask*exp2_f(-m1)};
  }
  // row 16: logits all 0, row max = 0 -> K entries exactly 1 (pad col: cmask)

  float vj0=1.f, vj1=1.f, vj2=1.f, vj3=1.f;
  float v16 = cmask;
  floatx2 u2[8];
  float u16;

  for (int r=0;r<40;++r){
    floatx2 b0=(floatx2){vj0,vj0}, b1=(floatx2){vj1,vj1};
    floatx2 b2=(floatx2){vj2,vj2}, b3=(floatx2){vj3,vj3};
    floatx2 b16=(floatx2){v16,v16};
    // ---- row normalization: u_i = 1 / sum_j K_ij v_j ----
#pragma unroll
    for (int k=0;k<8;++k){
      floatx2 pp = pk_mul2(Kp[0][k], b0);
      pp = pk_fma2(Kp[1][k], b1, pp);
      pp = pk_fma2(Kp[2][k], b2, pp);
      pp = pk_fma2(Kp[3][k], b3, pp);
      pp = pk_fma2(KPp[k], b16, pp);
      float px = qadd2(pp.x);
      float py = qadd2(pp.y);
      u2[k] = (floatx2){rcp_f(px), rcp_f(py)};
    }
    {
      // row 16: K == 1 across real cols, cmask on pad col; a_16 = I = 16
      float p16 = (vj0+vj1) + (vj2+vj3) + cmask*v16;
      p16 = qadd2(p16);
      u16 = 16.0f * rcp_f(p16);
    }
    // ---- column normalization: v_j = 1 / sum_i K_ij u_i ----
    floatx2 t0p = pk_mul2(Kp[0][0], u2[0]);
    floatx2 t1p = pk_mul2(Kp[1][0], u2[0]);
    floatx2 t2p = pk_mul2(Kp[2][0], u2[0]);
    floatx2 t3p = pk_mul2(Kp[3][0], u2[0]);
    floatx2 tPp = pk_mul2(KPp[0],   u2[0]);
#pragma unroll
    for (int k=1;k<8;++k){
      t0p = pk_fma2(Kp[0][k], u2[k], t0p);
      t1p = pk_fma2(Kp[1][k], u2[k], t1p);
      t2p = pk_fma2(Kp[2][k], u2[k], t2p);
      t3p = pk_fma2(Kp[3][k], u2[k], t3p);
      tPp = pk_fma2(KPp[k],   u2[k], tPp);
    }
    float t0 = t0p.x + t0p.y + u16;        // row-16 K == 1
    float t1 = t1p.x + t1p.y + u16;
    float t2 = t2p.x + t2p.y + u16;
    float t3 = t3p.x + t3p.y + u16;
    float t16 = tPp.x + tPp.y + cmask*u16;
    vj0 = rcp_f(t0); vj1 = rcp_f(t1); vj2 = rcp_f(t2); vj3 = rcp_f(t3);
    v16 = cmask * 16.0f * rcp_f(t16 + 1e-30f + (1.0f - cmask));  // b_16 = A = 16; NaN-guard off-lane
  }

  // ---- allocs = u_i K_ij v_j (write) + payments dot fused (reuse w) ----
  float* op = out + e*256 + 4*c;
  const float* bpx = X + e*256 + 4*c;
  float pv0=0.f, pv1=0.f, pv2=0.f, pv3=0.f;
#pragma unroll
  for (int k=0;k<8;++k){
#pragma unroll
    for (int h=0;h<2;++h){
      const int i = 2*k + h;
      const float uu = h ? u2[k].y : u2[k].x;
      const float K0 = h ? Kp[0][k].y : Kp[0][k].x;
      const float K1 = h ? Kp[1][k].y : Kp[1][k].x;
      const float K2 = h ? Kp[2][k].y : Kp[2][k].x;
      const float K3 = h ? Kp[3][k].y : Kp[3][k].x;
      float4 w;
      w.x = uu*K0*vj0;
      w.y = uu*K1*vj1;
      w.z = uu*K2*vj2;
      w.w = uu*K3*vj3;
      *(float4*)(op + i*16) = w;
      float4 bb = *(const float4*)(bpx + i*16);
      float s = w.x*bb.x + w.y*bb.y + w.z*bb.z + w.w*bb.w;
      s = qadd2(s);
      if ((i>>2) == c){
        const int rr = i & 3;
        if      (rr==0) pv0 = s;
        else if (rr==1) pv1 = s;
        else if (rr==2) pv2 = s;
        else            pv3 = s;
      }
    }
  }
  const float4 fr = *(const float4*)(frac_l + eL*16 + 4*c);
  float4 pvv;
  pvv.x = pv0*fr.x; pvv.y = pv1*fr.y; pvv.z = pv2*fr.z; pvv.w = pv3*fr.w;
  *(float4*)(out + (size_t)NB*256 + e*16 + 4*c) = pvv;
}

// ================= launch =================
extern "C" void kernel_launch(void* const* d_in, const int* in_sizes, int n_in,
                              void* d_out, int out_size, void* d_ws, size_t ws_size,
                              hipStream_t stream)
{
  const float* bids = (const float*)d_in[0];
  const float* aw0 = (const float*)d_in[1];  const float* ab0 = (const float*)d_in[2];
  const float* aw1 = (const float*)d_in[3];  const float* ab1 = (const float*)d_in[4];
  const float* aw2 = (const float*)d_in[5];  const float* ab2 = (const float*)d_in[6];
  const float* aw3 = (const float*)d_in[7];  const float* ab3 = (const float*)d_in[8];
  const float* pw0 = (const float*)d_in[9];  const float* pb0 = (const float*)d_in[10];
  const float* pw1 = (const float*)d_in[11]; const float* pb1 = (const float*)d_in[12];
  const float* pw2 = (const float*)d_in[13]; const float* pb2 = (const float*)d_in[14];
  const float* pw3 = (const float*)d_in[15]; const float* pb3 = (const float*)d_in[16];

  // f16 transposed/split weights in workspace (no d_out aliasing — fused kernel
  // writes payments while other blocks still read WT)
  _Float16* WT = (_Float16*)d_ws;

  PrepJobs js;
  js.j[0] = { aw0, WT+O_AW0H, nullptr,    8, 32768 };
  js.j[1] = { aw1, WT+O_AW1H, WT+O_AW1L,  7, 16384 };
  js.j[2] = { aw2, WT+O_AW2H, WT+O_AW2L,  7, 16384 };
  js.j[3] = { aw3, WT+O_AW3H, WT+O_AW3L,  7, 32768 };
  js.j[4] = { pw0, WT+O_PW0H, nullptr,    8, 32768 };
  js.j[5] = { pw1, WT+O_PW1H, nullptr,    7, 16384 };
  js.j[6] = { pw2, WT+O_PW2H, nullptr,    7, 16384 };
  js.j[7] = { pw3, WT+O_PW3H, nullptr,    7, 2048  };

  prep_kernel<<<dim3(128,8), 256, 0, stream>>>(js);
  fused_kernel<<<dim3(NB/16), 64, 0, stream>>>(bids, WT, ab0,ab1,ab2,ab3,
                                               pb0,pb1,pb2,pb3, (float*)d_out);
}

// Round 3
// 241.184 us; speedup vs baseline: 1.0973x; 1.0569x over previous
//
#include <hip/hip_runtime.h>

#define NB 32768

typedef _Float16 half8 __attribute__((ext_vector_type(8)));
typedef float floatx4 __attribute__((ext_vector_type(4)));
typedef float floatx2 __attribute__((ext_vector_type(2)));
typedef unsigned int uint4v __attribute__((ext_vector_type(4)));

#define MFMA16(a,b,c) __builtin_amdgcn_mfma_f32_16x16x32_f16(a,b,c,0,0,0)

// ---------- fast math ----------
__device__ __forceinline__ float rcp_f(float x){ return __builtin_amdgcn_rcpf(x); }
__device__ __forceinline__ float exp2_f(float x){ return __builtin_amdgcn_exp2f(x); }
__device__ __forceinline__ float tanh_f(float x){
  float e = exp2_f(x * 2.8853900817779268f);     // e^(2x)
  return (e - 1.0f) * rcp_f(e + 1.0f);
}
__device__ __forceinline__ float sigmoid_f(float x){
  return rcp_f(1.0f + exp2_f(-1.4426950408889634f * x));
}

// packed f32 math (VOP3P) — halves fma/mul issue count in Sinkhorn
__device__ __forceinline__ floatx2 pk_mul2(floatx2 a, floatx2 b){
  floatx2 d; asm("v_pk_mul_f32 %0, %1, %2" : "=v"(d) : "v"(a), "v"(b)); return d;
}
__device__ __forceinline__ floatx2 pk_fma2(floatx2 a, floatx2 b, floatx2 c){
  floatx2 d; asm("v_pk_fma_f32 %0, %1, %2, %3" : "=v"(d) : "v"(a), "v"(b), "v"(c)); return d;
}

// DPP quad butterflies: xor1 = quad_perm[1,0,3,2]=0xB1, xor2 = [2,3,0,1]=0x4E
template<int CTRL>
__device__ __forceinline__ float dpp_qp(float x){
  return __builtin_bit_cast(float, __builtin_amdgcn_update_dpp(0, __builtin_bit_cast(int,x), CTRL, 0xF, 0xF, true));
}
__device__ __forceinline__ float qadd2(float x){
  x += dpp_qp<0xB1>(x);
  x += dpp_qp<0x4E>(x);
  return x;
}
__device__ __forceinline__ float qmax2(float x){
  x = fmaxf(x, dpp_qp<0xB1>(x));
  x = fmaxf(x, dpp_qp<0x4E>(x));
  return x;
}

// ---------- f16 weight region offsets (in _Float16 units), lives in d_ws ----------
constexpr int O_AW0H = 0;        // 256x128
constexpr int O_AW1H = 32768;    // 128x128
constexpr int O_AW2H = 49152;
constexpr int O_AW3H = 65536;    // 128x256
constexpr int O_PW0H = 98304;
constexpr int O_PW1H = 131072;
constexpr int O_PW2H = 147456;
constexpr int O_PW3H = 163840;   // 128x16
constexpr int O_AW1L = 165888;
constexpr int O_AW2L = 182272;
constexpr int O_AW3L = 198656;

// ---------- weight prep: transpose + split f32 -> f16 hi/lo ----------
// Coalesced READS (consecutive threads -> consecutive src addresses); writes are
// scattered (stride-K u16) but posted — no wave stall.
struct PrepJob { const float* src; _Float16* h; _Float16* l; int nshift; int total; };
struct PrepJobs { PrepJob j[8]; };

__global__ void prep_kernel(PrepJobs js){
  const PrepJob jb = js.j[blockIdx.y];
  const int idx = blockIdx.x*256 + threadIdx.x;
  if (idx >= jb.total) return;
  const int N = 1 << jb.nshift;
  const int n = idx & (N-1);           // fastest-varying -> coalesced src read
  const int k = idx >> jb.nshift;
  const int K = jb.total >> jb.nshift;
  float w = jb.src[idx];               // src[k*N + n] == src[idx]
  _Float16 h = (_Float16)w;
  jb.h[(long)n*K + k] = h;
  if (jb.l) jb.l[(long)n*K + k] = (_Float16)(w - (float)h);
}

// ---------- LDS activation layout: 16 rows x 128 cols of packed (hi|lo) u32 ----------
// 16B-chunk XOR swizzle by (row&7)
__device__ __forceinline__ int aaddr(int row, int col){
  int cc = (col >> 2) ^ (row & 7);
  return row*128 + (cc<<2) + (col & 3);
}

template<bool NEED_LO>
__device__ __forceinline__ void read_frag(const unsigned int* __restrict__ act,
    int row, int ks, int q, half8& ah, half8& al)
{
  const int s = row & 7;
  const int cc0 = ks*8 + q*2;
  uint4v c0 = *(const uint4v*)(act + row*128 + (((cc0  ) ^ s)<<2));
  uint4v c1 = *(const uint4v*)(act + row*128 + (((cc0+1) ^ s)<<2));
  uint4v h;
  h.x = (c0.x & 0xffffu) | (c0.y << 16);
  h.y = (c0.z & 0xffffu) | (c0.w << 16);
  h.z = (c1.x & 0xffffu) | (c1.y << 16);
  h.w = (c1.z & 0xffffu) | (c1.w << 16);
  ah = __builtin_bit_cast(half8, h);
  if constexpr (NEED_LO){
    uint4v g;
    g.x = (c0.x >> 16) | (c0.y & 0xffff0000u);
    g.y = (c0.z >> 16) | (c0.w & 0xffff0000u);
    g.z = (c1.x >> 16) | (c1.y & 0xffff0000u);
    g.w = (c1.z >> 16) | (c1.w & 0xffff0000u);
    al = __builtin_bit_cast(half8, g);
  }
}

__device__ __forceinline__ unsigned int pack_act(float v){
  _Float16 h = (_Float16)v;
  _Float16 lo = (_Float16)(v - (float)h);
  return (unsigned int)__builtin_bit_cast(unsigned short, h)
       | ((unsigned int)__builtin_bit_cast(unsigned short, lo) << 16);
}
// p-net never reads the lo half -> hi-only pack
__device__ __forceinline__ unsigned int pack_act_hi(float v){
  return (unsigned int)__builtin_bit_cast(unsigned short, (_Float16)v);
}

// ---------- MFMA inner block with DOUBLE-BUFFERED weight prefetch ----------
// Loads all B-frags of n-tile nt+1 while MFMA'ing nt; all indices compile-time
// (unrolled) so the stage buffers stay in registers. In-flight window:
// KS*(PASSES==3?2:1) 16B loads during each tile's MFMAs.
template<int KS, int PASSES, int NT>
__device__ __forceinline__ void mfma_block(
    const half8* Ah, const half8* Al,
    const _Float16* __restrict__ Wh, const _Float16* __restrict__ Wl,
    int K, int l15, int q, floatx4* acc)
{
  half8 Bh[2][KS], Bl[2][KS];

  // prologue: stage 0
  {
    const _Float16* bp = Wh + l15*K + q*8;
#pragma unroll
    for (int ks=0; ks<KS; ++ks) Bh[0][ks] = *(const half8*)(bp + ks*32);
    if constexpr (PASSES == 3){
      const _Float16* blp = Wl + l15*K + q*8;
#pragma unroll
      for (int ks=0; ks<KS; ++ks) Bl[0][ks] = *(const half8*)(blp + ks*32);
    }
  }
#pragma unroll
  for (int nt=0; nt<NT; ++nt){
    if (nt+1 < NT){
      const _Float16* bp = Wh + ((nt+1)*16 + l15)*K + q*8;
#pragma unroll
      for (int ks=0; ks<KS; ++ks) Bh[(nt+1)&1][ks] = *(const half8*)(bp + ks*32);
      if constexpr (PASSES == 3){
        const _Float16* blp = Wl + ((nt+1)*16 + l15)*K + q*8;
#pragma unroll
        for (int ks=0; ks<KS; ++ks) Bl[(nt+1)&1][ks] = *(const half8*)(blp + ks*32);
      }
    }
#pragma unroll
    for (int ks=0; ks<KS; ++ks){
      acc[nt] = MFMA16(Ah[ks], Bh[nt&1][ks], acc[nt]);
      if constexpr (PASSES == 3){
        acc[nt] = MFMA16(Al[ks], Bh[nt&1][ks], acc[nt]);
        acc[nt] = MFMA16(Ah[ks], Bl[nt&1][ks], acc[nt]);
      }
    }
  }
}

// epilogue: bias+tanh+pack to LDS; rows q*4 + r
template<bool LO>
__device__ __forceinline__ void epi_tanh(floatx4* acc, const float* __restrict__ bias,
    unsigned int* __restrict__ act, int q, int l15)
{
#pragma unroll
  for (int nt=0; nt<8; ++nt){
    float bb = bias[nt*16 + l15];
#pragma unroll
    for (int r=0; r<4; ++r){
      float t = tanh_f(acc[nt][r] + bb);
      act[aaddr(q*4 + r, nt*16 + l15)] = LO ? pack_act(t) : pack_act_hi(t);
    }
  }
}

template<int PASSES>
__device__ __forceinline__ void hidden128(unsigned int* __restrict__ act,
    const _Float16* __restrict__ Wh, const _Float16* __restrict__ Wl,
    const float* __restrict__ bias, int q, int l15)
{
  half8 Ah[4], Al[4];
#pragma unroll
  for (int ks=0; ks<4; ++ks)
    read_frag<PASSES==3>(act, l15, ks, q, Ah[ks], Al[ks]);
  floatx4 acc[8];
#pragma unroll
  for (int nt=0; nt<8; ++nt) acc[nt] = (floatx4)0.0f;
  mfma_block<4,PASSES,8>(Ah, Al, Wh, Wl, 128, l15, q, acc);
  epi_tanh<PASSES==3>(acc, bias, act, q, l15);
}

// ================= Fused kernel: MLPs + Sinkhorn + payments =================
// 64 threads = 1 wave per block, 16 rows/block. Zero barriers (all LDS traffic is
// wave-local; LDS ops execute in issue order within a wave).
// LDS map: S[0..2048) = act_a (u32 hi|lo), S[2048..4096) = act_p,
//          S[0..4096) REUSED as aug f32 (16 rows x 256) after pL4 (act_p dead) and
//          after aL4 pre-loads act_a into registers. S[4096..4352) = frac f32.
// Occupancy is LDS-capped (~9 blocks/CU) -> extra VGPRs for prefetch are free.
__global__ __launch_bounds__(64, 2) void fused_kernel(
  const float* __restrict__ X, const _Float16* __restrict__ WT,
  const float* __restrict__ ab0, const float* __restrict__ ab1,
  const float* __restrict__ ab2, const float* __restrict__ ab3,
  const float* __restrict__ pb0, const float* __restrict__ pb1,
  const float* __restrict__ pb2, const float* __restrict__ pb3,
  float* __restrict__ out)
{
  __shared__ unsigned int S[16*256 + 256];   // 17408 B
  unsigned int* act_a = S;
  unsigned int* act_p = S + 2048;
  float* frac_l = (float*)(S + 4096);
  const int l = threadIdx.x, q = l>>4, l15 = l&15;
  const long rb = (long)blockIdx.x * 16;

  // ---- L1 of both nets from one X fragment set (K=256) ----
  {
    // batch ALL X loads first (16 dwordx4 in flight), convert after
    float4 xa[8], xb[8];
#pragma unroll
    for (int ks=0; ks<8; ++ks){
      const float* xp = X + (rb + l15)*256 + ks*32 + q*8;
      xa[ks] = *(const float4*)(xp);
      xb[ks] = *(const float4*)(xp + 4);
    }
    half8 Xf[8];
#pragma unroll
    for (int ks=0; ks<8; ++ks){
      half8 h;
      h[0]=(_Float16)xa[ks].x; h[1]=(_Float16)xa[ks].y; h[2]=(_Float16)xa[ks].z; h[3]=(_Float16)xa[ks].w;
      h[4]=(_Float16)xb[ks].x; h[5]=(_Float16)xb[ks].y; h[6]=(_Float16)xb[ks].z; h[7]=(_Float16)xb[ks].w;
      Xf[ks] = h;
    }
    floatx4 acca[8], accp[8];
#pragma unroll
    for (int nt=0; nt<8; ++nt){ acca[nt] = (floatx4)0.0f; accp[nt] = (floatx4)0.0f; }
    mfma_block<8,1,8>(Xf, Xf, WT+O_AW0H, WT+O_AW0H, 256, l15, q, acca);
    mfma_block<8,1,8>(Xf, Xf, WT+O_PW0H, WT+O_PW0H, 256, l15, q, accp);
    epi_tanh<true >(acca, ab0, act_a, q, l15);
    epi_tanh<false>(accp, pb0, act_p, q, l15);
  }
  // ---- hidden layers interleaved: a (3-pass split-corrected), p (1-pass) ----
  hidden128<3>(act_a, WT+O_AW1H, WT+O_AW1L, ab1, q, l15);
  hidden128<1>(act_p, WT+O_PW1H, WT+O_PW1H, pb1, q, l15);
  hidden128<3>(act_a, WT+O_AW2H, WT+O_AW2L, ab2, q, l15);
  hidden128<1>(act_p, WT+O_PW2H, WT+O_PW2H, pb2, q, l15);

  // ---- p-net L4 -> frac (sigmoid) to LDS — MUST precede aL4's aug overlay ----
  {
    half8 Ah[4], Al[4];
#pragma unroll
    for (int ks=0; ks<4; ++ks)
      read_frag<false>(act_p, l15, ks, q, Ah[ks], Al[ks]);
    floatx4 acc1 = (floatx4)0.0f;
    mfma_block<4,1,1>(Ah, Ah, WT+O_PW3H, WT+O_PW3H, 128, l15, q, &acc1);
    float bb = pb3[l15];
#pragma unroll
    for (int r=0; r<4; ++r)
      frac_l[(q*4+r)*16 + l15] = sigmoid_f(acc1[r] + bb);
  }
  // ---- a-net L4 -> aug (f32) into LDS overlay; act_a fully pre-read to regs ----
  {
    half8 Ah[4], Al[4];
#pragma unroll
    for (int ks=0; ks<4; ++ks)
      read_frag<true>(act_a, l15, ks, q, Ah[ks], Al[ks]);
    float* augl = (float*)S;
#pragma unroll
    for (int hf=0; hf<2; ++hf){
      floatx4 acc[8];
#pragma unroll
      for (int nt=0; nt<8; ++nt) acc[nt] = (floatx4)0.0f;
      mfma_block<4,3,8>(Ah, Al, WT+O_AW3H + hf*128*128, WT+O_AW3L + hf*128*128, 128, l15, q, acc);
      const int ncol0 = hf*128;
#pragma unroll
      for (int nt=0; nt<8; ++nt){
        float bb = ab3[ncol0 + nt*16 + l15];
#pragma unroll
        for (int r=0; r<4; ++r)
          augl[(q*4+r)*256 + ncol0 + nt*16 + l15] = acc[nt][r] + bb;
      }
    }
  }

  // ================= Sinkhorn + payments (wave-local, pk-f32 packed) =================
  // Lane owns 4 columns (4c..4c+3). K stored row-PAIR-packed (floatx2 over i).
  // Row 16 of the padded matrix has all-zero logits -> after max-subtract its K
  // entries are exactly 1 (pad col: cmask) -> constant-folded scalar path.
  const int c = l & 3;
  const int eL = l >> 2;                 // local element 0..15
  const long e = rb + eL;                // global element
  const float Ssc = 14.426950408889634f; // (1/EPS)/ln2 : logits in exp2 units
  const float cmask = (c == 3) ? 1.0f : 0.0f;

  floatx2 Kp[4][8];   // owned columns, rows (2k, 2k+1)
  floatx2 KPp[8];     // pad column 16 (lane 3 only; zero elsewhere), row-pairs

  const float* ap = (const float*)S + eL*256 + 4*c;
#pragma unroll
  for (int k=0;k<8;++k){
    float4 va = *(const float4*)(ap + (2*k  )*16);
    float4 vb = *(const float4*)(ap + (2*k+1)*16);
    Kp[0][k] = (floatx2){va.x*Ssc, vb.x*Ssc};
    Kp[1][k] = (floatx2){va.y*Ssc, vb.y*Ssc};
    Kp[2][k] = (floatx2){va.z*Ssc, vb.z*Ssc};
    Kp[3][k] = (floatx2){va.w*Ssc, vb.w*Ssc};
  }

  // max-subtract + exponentiate (row-wise, across the 4 lanes + pad col 0)
#pragma unroll
  for (int k=0;k<8;++k){
    float m0 = fmaxf(fmaxf(Kp[0][k].x,Kp[1][k].x), fmaxf(Kp[2][k].x,Kp[3][k].x));
    m0 = qmax2(fmaxf(m0, 0.0f));
    float m1 = fmaxf(fmaxf(Kp[0][k].y,Kp[1][k].y), fmaxf(Kp[2][k].y,Kp[3][k].y));
    m1 = qmax2(fmaxf(m1, 0.0f));
    Kp[0][k] = (floatx2){exp2_f(Kp[0][k].x-m0), exp2_f(Kp[0][k].y-m1)};
    Kp[1][k] = (floatx2){exp2_f(Kp[1][k].x-m0), exp2_f(Kp[1][k].y-m1)};
    Kp[2][k] = (floatx2){exp2_f(Kp[2][k].x-m0), exp2_f(Kp[2][k].y-m1)};
    Kp[3][k] = (floatx2){exp2_f(Kp[3][k].x-m0), exp2_f(Kp[3][k].y-m1)};
    KPp[k]   = (floatx2){cmask*exp2_f(-m0), cmask*exp2_f(-m1)};
  }
  // row 16: logits all 0, row max = 0 -> K entries exactly 1 (pad col: cmask)

  float vj0=1.f, vj1=1.f, vj2=1.f, vj3=1.f;
  float v16 = cmask;
  floatx2 u2[8];
  float u16;

  for (int r=0;r<40;++r){
    floatx2 b0=(floatx2){vj0,vj0}, b1=(floatx2){vj1,vj1};
    floatx2 b2=(floatx2){vj2,vj2}, b3=(floatx2){vj3,vj3};
    floatx2 b16=(floatx2){v16,v16};
    // ---- row normalization: u_i = 1 / sum_j K_ij v_j ----
#pragma unroll
    for (int k=0;k<8;++k){
      floatx2 pp = pk_mul2(Kp[0][k], b0);
      pp = pk_fma2(Kp[1][k], b1, pp);
      pp = pk_fma2(Kp[2][k], b2, pp);
      pp = pk_fma2(Kp[3][k], b3, pp);
      pp = pk_fma2(KPp[k], b16, pp);
      float px = qadd2(pp.x);
      float py = qadd2(pp.y);
      u2[k] = (floatx2){rcp_f(px), rcp_f(py)};
    }
    {
      // row 16: K == 1 across real cols, cmask on pad col; a_16 = I = 16
      float p16 = (vj0+vj1) + (vj2+vj3) + cmask*v16;
      p16 = qadd2(p16);
      u16 = 16.0f * rcp_f(p16);
    }
    // ---- column normalization: v_j = 1 / sum_i K_ij u_i ----
    floatx2 t0p = pk_mul2(Kp[0][0], u2[0]);
    floatx2 t1p = pk_mul2(Kp[1][0], u2[0]);
    floatx2 t2p = pk_mul2(Kp[2][0], u2[0]);
    floatx2 t3p = pk_mul2(Kp[3][0], u2[0]);
    floatx2 tPp = pk_mul2(KPp[0],   u2[0]);
#pragma unroll
    for (int k=1;k<8;++k){
      t0p = pk_fma2(Kp[0][k], u2[k], t0p);
      t1p = pk_fma2(Kp[1][k], u2[k], t1p);
      t2p = pk_fma2(Kp[2][k], u2[k], t2p);
      t3p = pk_fma2(Kp[3][k], u2[k], t3p);
      tPp = pk_fma2(KPp[k],   u2[k], tPp);
    }
    float t0 = t0p.x + t0p.y + u16;        // row-16 K == 1
    float t1 = t1p.x + t1p.y + u16;
    float t2 = t2p.x + t2p.y + u16;
    float t3 = t3p.x + t3p.y + u16;
    float t16 = tPp.x + tPp.y + cmask*u16;
    vj0 = rcp_f(t0); vj1 = rcp_f(t1); vj2 = rcp_f(t2); vj3 = rcp_f(t3);
    v16 = cmask * 16.0f * rcp_f(t16 + 1e-30f + (1.0f - cmask));  // b_16 = A = 16; NaN-guard off-lane
  }

  // ---- allocs = u_i K_ij v_j (write) + payments dot fused (reuse w) ----
  float* op = out + e*256 + 4*c;
  const float* bpx = X + e*256 + 4*c;
  float pv0=0.f, pv1=0.f, pv2=0.f, pv3=0.f;
#pragma unroll
  for (int k=0;k<8;++k){
#pragma unroll
    for (int h=0;h<2;++h){
      const int i = 2*k + h;
      const float uu = h ? u2[k].y : u2[k].x;
      const float K0 = h ? Kp[0][k].y : Kp[0][k].x;
      const float K1 = h ? Kp[1][k].y : Kp[1][k].x;
      const float K2 = h ? Kp[2][k].y : Kp[2][k].x;
      const float K3 = h ? Kp[3][k].y : Kp[3][k].x;
      float4 w;
      w.x = uu*K0*vj0;
      w.y = uu*K1*vj1;
      w.z = uu*K2*vj2;
      w.w = uu*K3*vj3;
      *(float4*)(op + i*16) = w;
      float4 bb = *(const float4*)(bpx + i*16);
      float s = w.x*bb.x + w.y*bb.y + w.z*bb.z + w.w*bb.w;
      s = qadd2(s);
      if ((i>>2) == c){
        const int rr = i & 3;
        if      (rr==0) pv0 = s;
        else if (rr==1) pv1 = s;
        else if (rr==2) pv2 = s;
        else            pv3 = s;
      }
    }
  }
  const float4 fr = *(const float4*)(frac_l + eL*16 + 4*c);
  float4 pvv;
  pvv.x = pv0*fr.x; pvv.y = pv1*fr.y; pvv.z = pv2*fr.z; pvv.w = pv3*fr.w;
  *(float4*)(out + (size_t)NB*256 + e*16 + 4*c) = pvv;
}

// ================= launch =================
extern "C" void kernel_launch(void* const* d_in, const int* in_sizes, int n_in,
                              void* d_out, int out_size, void* d_ws, size_t ws_size,
                              hipStream_t stream)
{
  const float* bids = (const float*)d_in[0];
  const float* aw0 = (const float*)d_in[1];  const float* ab0 = (const float*)d_in[2];
  const float* aw1 = (const float*)d_in[3];  const float* ab1 = (const float*)d_in[4];
  const float* aw2 = (const float*)d_in[5];  const float* ab2 = (const float*)d_in[6];
  const float* aw3 = (const float*)d_in[7];  const float* ab3 = (const float*)d_in[8];
  const float* pw0 = (const float*)d_in[9];  const float* pb0 = (const float*)d_in[10];
  const float* pw1 = (const float*)d_in[11]; const float* pb1 = (const float*)d_in[12];
  const float* pw2 = (const float*)d_in[13]; const float* pb2 = (const float*)d_in[14];
  const float* pw3 = (const float*)d_in[15]; const float* pb3 = (const float*)d_in[16];

  // f16 transposed/split weights in workspace (no d_out aliasing — fused kernel
  // writes payments while other blocks still read WT)
  _Float16* WT = (_Float16*)d_ws;

  // nshift = log2(N) where W is K x N (row-major src); dst is N x K (transposed)
  PrepJobs js;
  js.j[0] = { aw0, WT+O_AW0H, nullptr,    7, 32768 };  // 256x128
  js.j[1] = { aw1, WT+O_AW1H, WT+O_AW1L,  7, 16384 };  // 128x128
  js.j[2] = { aw2, WT+O_AW2H, WT+O_AW2L,  7, 16384 };  // 128x128
  js.j[3] = { aw3, WT+O_AW3H, WT+O_AW3L,  8, 32768 };  // 128x256
  js.j[4] = { pw0, WT+O_PW0H, nullptr,    7, 32768 };  // 256x128
  js.j[5] = { pw1, WT+O_PW1H, nullptr,    7, 16384 };  // 128x128
  js.j[6] = { pw2, WT+O_PW2H, nullptr,    7, 16384 };  // 128x128
  js.j[7] = { pw3, WT+O_PW3H, nullptr,    4, 2048  };  // 128x16

  prep_kernel<<<dim3(128,8), 256, 0, stream>>>(js);
  fused_kernel<<<dim3(NB/16), 64, 0, stream>>>(bids, WT, ab0,ab1,ab2,ab3,
                                               pb0,pb1,pb2,pb3, (float*)d_out);
}

// Round 4
// 235.991 us; speedup vs baseline: 1.1214x; 1.0220x over previous
//
#include <hip/hip_runtime.h>

#define NB 32768

typedef _Float16 half8 __attribute__((ext_vector_type(8)));
typedef float floatx4 __attribute__((ext_vector_type(4)));
typedef float floatx2 __attribute__((ext_vector_type(2)));
typedef unsigned int uint4v __attribute__((ext_vector_type(4)));

#define MFMA16(a,b,c) __builtin_amdgcn_mfma_f32_16x16x32_f16(a,b,c,0,0,0)

// ---------- fast math ----------
__device__ __forceinline__ float rcp_f(float x){ return __builtin_amdgcn_rcpf(x); }
__device__ __forceinline__ float exp2_f(float x){ return __builtin_amdgcn_exp2f(x); }
__device__ __forceinline__ float tanh_f(float x){
  float e = exp2_f(x * 2.8853900817779268f);     // e^(2x)
  return (e - 1.0f) * rcp_f(e + 1.0f);
}
__device__ __forceinline__ float sigmoid_f(float x){
  return rcp_f(1.0f + exp2_f(-1.4426950408889634f * x));
}

// packed f32 math (VOP3P) — halves fma/mul issue count in Sinkhorn
__device__ __forceinline__ floatx2 pk_mul2(floatx2 a, floatx2 b){
  floatx2 d; asm("v_pk_mul_f32 %0, %1, %2" : "=v"(d) : "v"(a), "v"(b)); return d;
}
__device__ __forceinline__ floatx2 pk_fma2(floatx2 a, floatx2 b, floatx2 c){
  floatx2 d; asm("v_pk_fma_f32 %0, %1, %2, %3" : "=v"(d) : "v"(a), "v"(b), "v"(c)); return d;
}

// DPP quad butterflies: xor1 = quad_perm[1,0,3,2]=0xB1, xor2 = [2,3,0,1]=0x4E
template<int CTRL>
__device__ __forceinline__ float dpp_qp(float x){
  return __builtin_bit_cast(float, __builtin_amdgcn_update_dpp(0, __builtin_bit_cast(int,x), CTRL, 0xF, 0xF, true));
}
__device__ __forceinline__ float qadd2(float x){
  x += dpp_qp<0xB1>(x);
  x += dpp_qp<0x4E>(x);
  return x;
}
__device__ __forceinline__ float qmax2(float x){
  x = fmaxf(x, dpp_qp<0xB1>(x));
  x = fmaxf(x, dpp_qp<0x4E>(x));
  return x;
}

// ---------- f16 weight region offsets (in _Float16 units), lives in d_ws ----------
constexpr int O_AW0H = 0;        // 256x128
constexpr int O_AW1H = 32768;    // 128x128
constexpr int O_AW2H = 49152;
constexpr int O_AW3H = 65536;    // 128x256
constexpr int O_PW0H = 98304;
constexpr int O_PW1H = 131072;
constexpr int O_PW2H = 147456;
constexpr int O_PW3H = 163840;   // 128x16
constexpr int O_AW1L = 165888;
constexpr int O_AW2L = 182272;
constexpr int O_AW3L = 198656;

// ---------- weight prep: transpose + split f32 -> f16 hi/lo ----------
// Coalesced READS; writes scattered (posted, no wave stall).
struct PrepJob { const float* src; _Float16* h; _Float16* l; int nshift; int total; };
struct PrepJobs { PrepJob j[8]; };

__global__ void prep_kernel(PrepJobs js){
  const PrepJob jb = js.j[blockIdx.y];
  const int idx = blockIdx.x*256 + threadIdx.x;
  if (idx >= jb.total) return;
  const int N = 1 << jb.nshift;
  const int n = idx & (N-1);           // fastest-varying -> coalesced src read
  const int k = idx >> jb.nshift;
  const int K = jb.total >> jb.nshift;
  float w = jb.src[idx];               // src[k*N + n] == src[idx]
  _Float16 h = (_Float16)w;
  jb.h[(long)n*K + k] = h;
  if (jb.l) jb.l[(long)n*K + k] = (_Float16)(w - (float)h);
}

// ---------- LDS activation layout: 16 rows x 128 cols of packed (hi|lo) u32 ----------
// 16B-chunk XOR swizzle by (row&7)
__device__ __forceinline__ int aaddr(int row, int col){
  int cc = (col >> 2) ^ (row & 7);
  return row*128 + (cc<<2) + (col & 3);
}

template<bool NEED_LO>
__device__ __forceinline__ void read_frag(const unsigned int* __restrict__ act,
    int row, int ks, int q, half8& ah, half8& al)
{
  const int s = row & 7;
  const int cc0 = ks*8 + q*2;
  uint4v c0 = *(const uint4v*)(act + row*128 + (((cc0  ) ^ s)<<2));
  uint4v c1 = *(const uint4v*)(act + row*128 + (((cc0+1) ^ s)<<2));
  uint4v h;
  h.x = (c0.x & 0xffffu) | (c0.y << 16);
  h.y = (c0.z & 0xffffu) | (c0.w << 16);
  h.z = (c1.x & 0xffffu) | (c1.y << 16);
  h.w = (c1.z & 0xffffu) | (c1.w << 16);
  ah = __builtin_bit_cast(half8, h);
  if constexpr (NEED_LO){
    uint4v g;
    g.x = (c0.x >> 16) | (c0.y & 0xffff0000u);
    g.y = (c0.z >> 16) | (c0.w & 0xffff0000u);
    g.z = (c1.x >> 16) | (c1.y & 0xffff0000u);
    g.w = (c1.z >> 16) | (c1.w & 0xffff0000u);
    al = __builtin_bit_cast(half8, g);
  }
}

__device__ __forceinline__ unsigned int pack_act(float v){
  _Float16 h = (_Float16)v;
  _Float16 lo = (_Float16)(v - (float)h);
  return (unsigned int)__builtin_bit_cast(unsigned short, h)
       | ((unsigned int)__builtin_bit_cast(unsigned short, lo) << 16);
}
// p-net never reads the lo half -> hi-only pack
__device__ __forceinline__ unsigned int pack_act_hi(float v){
  return (unsigned int)__builtin_bit_cast(unsigned short, (_Float16)v);
}

// ---------- load one weight tile's fragments into a register stage ----------
template<int KS, bool LO>
__device__ __forceinline__ void load_tile(
    const _Float16* __restrict__ Wh, const _Float16* __restrict__ Wl,
    int K, int nt, int l15, int q, half8* bh, half8* bl)
{
  const _Float16* bp = Wh + (nt*16 + l15)*K + q*8;
#pragma unroll
  for (int ks=0; ks<KS; ++ks) bh[ks] = *(const half8*)(bp + ks*32);
  if constexpr (LO){
    const _Float16* blp = Wl + (nt*16 + l15)*K + q*8;
#pragma unroll
    for (int ks=0; ks<KS; ++ks) bl[ks] = *(const half8*)(blp + ks*32);
  }
}

// ---------- MFMA stream: depth-2 ring-3 prefetch + PER-TILE epilogue ----------
// Per tile-slot: [issue loads nt+2] -> [MFMAs nt, split into 2 acc chains] ->
// [epi(nt) VALU] — the MFMA+epi work (~200cyc) covers the in-flight loads.
template<int KS, int PASSES, int NT, typename EPI>
__device__ __forceinline__ void mfma_stream(
    const half8* Ah, const half8* Al,
    const _Float16* __restrict__ Wh, const _Float16* __restrict__ Wl,
    int K, int l15, int q, EPI&& epi)
{
  half8 Bh[3][KS], Bl[3][KS];
  load_tile<KS,PASSES==3>(Wh, Wl, K, 0, l15, q, Bh[0], Bl[0]);
  if constexpr (NT > 1)
    load_tile<KS,PASSES==3>(Wh, Wl, K, 1, l15, q, Bh[1], Bl[1]);
#pragma unroll
  for (int nt=0; nt<NT; ++nt){
    if (nt+2 < NT)
      load_tile<KS,PASSES==3>(Wh, Wl, K, nt+2, l15, q, Bh[(nt+2)%3], Bl[(nt+2)%3]);
    floatx4 a0 = (floatx4)0.0f, a1 = (floatx4)0.0f;   // 2 chains (even/odd ks)
#pragma unroll
    for (int ks=0; ks<KS; ++ks){
      floatx4& ac = (ks & 1) ? a1 : a0;
      ac = MFMA16(Ah[ks], Bh[nt%3][ks], ac);
      if constexpr (PASSES == 3){
        ac = MFMA16(Al[ks], Bh[nt%3][ks], ac);
        ac = MFMA16(Ah[ks], Bl[nt%3][ks], ac);
      }
    }
    floatx4 acc;
#pragma unroll
    for (int r=0; r<4; ++r) acc[r] = a0[r] + a1[r];
    epi(nt, acc);
  }
}

// ================= Fused kernel: MLPs + Sinkhorn + payments =================
// 64 threads = 1 wave per block, 16 rows/block. Zero barriers (all LDS traffic is
// wave-local; LDS ops execute in issue order within a wave).
// LDS map: S[0..2048) = act_a (u32 hi|lo), S[2048..4096) = act_p,
//          S[0..4096) REUSED as aug f32 (16 rows x 256) after pL4 (act_p dead) and
//          after aL4 pre-loads act_a into registers. S[4096..4352) = frac f32.
// Occupancy LDS-capped (~9 blocks/CU) -> prefetch VGPRs are free up to 256.
__global__ __launch_bounds__(64, 2) void fused_kernel(
  const float* __restrict__ X, const _Float16* __restrict__ WT,
  const float* __restrict__ ab0, const float* __restrict__ ab1,
  const float* __restrict__ ab2, const float* __restrict__ ab3,
  const float* __restrict__ pb0, const float* __restrict__ pb1,
  const float* __restrict__ pb2, const float* __restrict__ pb3,
  float* __restrict__ out)
{
  __shared__ unsigned int S[16*256 + 256];   // 17408 B
  unsigned int* act_a = S;
  unsigned int* act_p = S + 2048;
  float* frac_l = (float*)(S + 4096);
  const int l = threadIdx.x, q = l>>4, l15 = l&15;
  const long rb = (long)blockIdx.x * 16;

  // per-tile epilogue makers
  auto epi_act = [&](unsigned int* act, const float* bias, bool lo){
    return [=](int nt, floatx4 acc){
      float bb = bias[nt*16 + l15];
#pragma unroll
      for (int r=0; r<4; ++r){
        float t = tanh_f(acc[r] + bb);
        act[aaddr(q*4 + r, nt*16 + l15)] = lo ? pack_act(t) : pack_act_hi(t);
      }
    };
  };

  // ---- L1 of both nets from one X fragment set (K=256) ----
  {
    // batch ALL X loads first (16 dwordx4 in flight), convert after
    float4 xa[8], xb[8];
#pragma unroll
    for (int ks=0; ks<8; ++ks){
      const float* xp = X + (rb + l15)*256 + ks*32 + q*8;
      xa[ks] = *(const float4*)(xp);
      xb[ks] = *(const float4*)(xp + 4);
    }
    half8 Xf[8];
#pragma unroll
    for (int ks=0; ks<8; ++ks){
      half8 h;
      h[0]=(_Float16)xa[ks].x; h[1]=(_Float16)xa[ks].y; h[2]=(_Float16)xa[ks].z; h[3]=(_Float16)xa[ks].w;
      h[4]=(_Float16)xb[ks].x; h[5]=(_Float16)xb[ks].y; h[6]=(_Float16)xb[ks].z; h[7]=(_Float16)xb[ks].w;
      Xf[ks] = h;
    }
    mfma_stream<8,1,8>(Xf, Xf, WT+O_AW0H, WT+O_AW0H, 256, l15, q, epi_act(act_a, ab0, true));
    mfma_stream<8,1,8>(Xf, Xf, WT+O_PW0H, WT+O_PW0H, 256, l15, q, epi_act(act_p, pb0, false));
  }

  // ---- hidden layers: a (3-pass hi/lo), p (1-pass), per-tile pipelined ----
  {
    half8 Ah[4], Al[4];
#pragma unroll
    for (int ks=0; ks<4; ++ks) read_frag<true>(act_a, l15, ks, q, Ah[ks], Al[ks]);
    mfma_stream<4,3,8>(Ah, Al, WT+O_AW1H, WT+O_AW1L, 128, l15, q, epi_act(act_a, ab1, true));
  }
  {
    half8 Ph[4], du;
#pragma unroll
    for (int ks=0; ks<4; ++ks) read_frag<false>(act_p, l15, ks, q, Ph[ks], du);
    mfma_stream<4,1,8>(Ph, Ph, WT+O_PW1H, WT+O_PW1H, 128, l15, q, epi_act(act_p, pb1, false));
  }
  {
    half8 Ah[4], Al[4];
#pragma unroll
    for (int ks=0; ks<4; ++ks) read_frag<true>(act_a, l15, ks, q, Ah[ks], Al[ks]);
    mfma_stream<4,3,8>(Ah, Al, WT+O_AW2H, WT+O_AW2L, 128, l15, q, epi_act(act_a, ab2, true));
  }
  {
    half8 Ph[4], du;
#pragma unroll
    for (int ks=0; ks<4; ++ks) read_frag<false>(act_p, l15, ks, q, Ph[ks], du);
    mfma_stream<4,1,8>(Ph, Ph, WT+O_PW2H, WT+O_PW2H, 128, l15, q, epi_act(act_p, pb2, false));
  }

  // ---- p-net L4 -> frac (sigmoid) to LDS — MUST precede aL4's aug overlay ----
  {
    half8 Ph[4], du;
#pragma unroll
    for (int ks=0; ks<4; ++ks) read_frag<false>(act_p, l15, ks, q, Ph[ks], du);
    mfma_stream<4,1,1>(Ph, Ph, WT+O_PW3H, WT+O_PW3H, 128, l15, q,
      [&](int, floatx4 acc){
        float bb = pb3[l15];
#pragma unroll
        for (int r=0; r<4; ++r)
          frac_l[(q*4+r)*16 + l15] = sigmoid_f(acc[r] + bb);
      });
  }
  // ---- a-net L4 -> aug (f32) into LDS overlay; act_a fully pre-read to regs ----
  {
    half8 Ah[4], Al[4];
#pragma unroll
    for (int ks=0; ks<4; ++ks) read_frag<true>(act_a, l15, ks, q, Ah[ks], Al[ks]);
    float* augl = (float*)S;
#pragma unroll
    for (int hf=0; hf<2; ++hf){
      const int ncol0 = hf*128;
      mfma_stream<4,3,8>(Ah, Al, WT+O_AW3H + hf*128*128, WT+O_AW3L + hf*128*128,
                         128, l15, q,
        [&](int nt, floatx4 acc){
          float bb = ab3[ncol0 + nt*16 + l15];
#pragma unroll
          for (int r=0; r<4; ++r)
            augl[(q*4+r)*256 + ncol0 + nt*16 + l15] = acc[r] + bb;
        });
    }
  }

  // ================= Sinkhorn + payments (wave-local, pk-f32 packed) =================
  // Lane owns 4 columns (4c..4c+3). K stored row-PAIR-packed (floatx2 over i).
  const int c = l & 3;
  const int eL = l >> 2;                 // local element 0..15
  const long e = rb + eL;                // global element
  const float Ssc = 14.426950408889634f; // (1/EPS)/ln2 : logits in exp2 units
  const float cmask = (c == 3) ? 1.0f : 0.0f;

  floatx2 Kp[4][8];   // owned columns, rows (2k, 2k+1)
  floatx2 KPp[8];     // pad column 16 (lane 3 only; zero elsewhere), row-pairs

  const float* ap = (const float*)S + eL*256 + 4*c;
#pragma unroll
  for (int k=0;k<8;++k){
    float4 va = *(const float4*)(ap + (2*k  )*16);
    float4 vb = *(const float4*)(ap + (2*k+1)*16);
    Kp[0][k] = (floatx2){va.x*Ssc, vb.x*Ssc};
    Kp[1][k] = (floatx2){va.y*Ssc, vb.y*Ssc};
    Kp[2][k] = (floatx2){va.z*Ssc, vb.z*Ssc};
    Kp[3][k] = (floatx2){va.w*Ssc, vb.w*Ssc};
  }

  // max-subtract + exponentiate (row-wise, across the 4 lanes + pad col 0)
#pragma unroll
  for (int k=0;k<8;++k){
    float m0 = fmaxf(fmaxf(Kp[0][k].x,Kp[1][k].x), fmaxf(Kp[2][k].x,Kp[3][k].x));
    m0 = qmax2(fmaxf(m0, 0.0f));
    float m1 = fmaxf(fmaxf(Kp[0][k].y,Kp[1][k].y), fmaxf(Kp[2][k].y,Kp[3][k].y));
    m1 = qmax2(fmaxf(m1, 0.0f));
    Kp[0][k] = (floatx2){exp2_f(Kp[0][k].x-m0), exp2_f(Kp[0][k].y-m1)};
    Kp[1][k] = (floatx2){exp2_f(Kp[1][k].x-m0), exp2_f(Kp[1][k].y-m1)};
    Kp[2][k] = (floatx2){exp2_f(Kp[2][k].x-m0), exp2_f(Kp[2][k].y-m1)};
    Kp[3][k] = (floatx2){exp2_f(Kp[3][k].x-m0), exp2_f(Kp[3][k].y-m1)};
    KPp[k]   = (floatx2){cmask*exp2_f(-m0), cmask*exp2_f(-m1)};
  }
  // row 16: logits all 0, row max = 0 -> K entries exactly 1 (pad col: cmask)

  float vj0=1.f, vj1=1.f, vj2=1.f, vj3=1.f;
  float v16 = cmask;
  floatx2 u2[8];
  float u16;

  for (int r=0;r<40;++r){
    floatx2 b0=(floatx2){vj0,vj0}, b1=(floatx2){vj1,vj1};
    floatx2 b2=(floatx2){vj2,vj2}, b3=(floatx2){vj3,vj3};
    floatx2 b16=(floatx2){v16,v16};
    // ---- row normalization: u_i = 1 / sum_j K_ij v_j ----
#pragma unroll
    for (int k=0;k<8;++k){
      floatx2 pp = pk_mul2(Kp[0][k], b0);
      pp = pk_fma2(Kp[1][k], b1, pp);
      pp = pk_fma2(Kp[2][k], b2, pp);
      pp = pk_fma2(Kp[3][k], b3, pp);
      pp = pk_fma2(KPp[k], b16, pp);
      float px = qadd2(pp.x);
      float py = qadd2(pp.y);
      u2[k] = (floatx2){rcp_f(px), rcp_f(py)};
    }
    {
      // row 16: K == 1 across real cols, cmask on pad col; a_16 = I = 16
      float p16 = (vj0+vj1) + (vj2+vj3) + cmask*v16;
      p16 = qadd2(p16);
      u16 = 16.0f * rcp_f(p16);
    }
    // ---- column normalization: v_j = 1 / sum_i K_ij u_i ----
    floatx2 t0p = pk_mul2(Kp[0][0], u2[0]);
    floatx2 t1p = pk_mul2(Kp[1][0], u2[0]);
    floatx2 t2p = pk_mul2(Kp[2][0], u2[0]);
    floatx2 t3p = pk_mul2(Kp[3][0], u2[0]);
    floatx2 tPp = pk_mul2(KPp[0],   u2[0]);
#pragma unroll
    for (int k=1;k<8;++k){
      t0p = pk_fma2(Kp[0][k], u2[k], t0p);
      t1p = pk_fma2(Kp[1][k], u2[k], t1p);
      t2p = pk_fma2(Kp[2][k], u2[k], t2p);
      t3p = pk_fma2(Kp[3][k], u2[k], t3p);
      tPp = pk_fma2(KPp[k],   u2[k], tPp);
    }
    float t0 = t0p.x + t0p.y + u16;        // row-16 K == 1
    float t1 = t1p.x + t1p.y + u16;
    float t2 = t2p.x + t2p.y + u16;
    float t3 = t3p.x + t3p.y + u16;
    float t16 = tPp.x + tPp.y + cmask*u16;
    vj0 = rcp_f(t0); vj1 = rcp_f(t1); vj2 = rcp_f(t2); vj3 = rcp_f(t3);
    v16 = cmask * 16.0f * rcp_f(t16 + 1e-30f + (1.0f - cmask));  // b_16 = A = 16; NaN-guard off-lane
  }

  // ---- allocs = u_i K_ij v_j (write) + payments dot fused (reuse w) ----
  float* op = out + e*256 + 4*c;
  const float* bpx = X + e*256 + 4*c;
  float pv0=0.f, pv1=0.f, pv2=0.f, pv3=0.f;
#pragma unroll
  for (int k=0;k<8;++k){
#pragma unroll
    for (int h=0;h<2;++h){
      const int i = 2*k + h;
      const float uu = h ? u2[k].y : u2[k].x;
      const float K0 = h ? Kp[0][k].y : Kp[0][k].x;
      const float K1 = h ? Kp[1][k].y : Kp[1][k].x;
      const float K2 = h ? Kp[2][k].y : Kp[2][k].x;
      const float K3 = h ? Kp[3][k].y : Kp[3][k].x;
      float4 w;
      w.x = uu*K0*vj0;
      w.y = uu*K1*vj1;
      w.z = uu*K2*vj2;
      w.w = uu*K3*vj3;
      *(float4*)(op + i*16) = w;
      float4 bb = *(const float4*)(bpx + i*16);
      float s = w.x*bb.x + w.y*bb.y + w.z*bb.z + w.w*bb.w;
      s = qadd2(s);
      if ((i>>2) == c){
        const int rr = i & 3;
        if      (rr==0) pv0 = s;
        else if (rr==1) pv1 = s;
        else if (rr==2) pv2 = s;
        else            pv3 = s;
      }
    }
  }
  const float4 fr = *(const float4*)(frac_l + eL*16 + 4*c);
  float4 pvv;
  pvv.x = pv0*fr.x; pvv.y = pv1*fr.y; pvv.z = pv2*fr.z; pvv.w = pv3*fr.w;
  *(float4*)(out + (size_t)NB*256 + e*16 + 4*c) = pvv;
}

// ================= launch =================
extern "C" void kernel_launch(void* const* d_in, const int* in_sizes, int n_in,
                              void* d_out, int out_size, void* d_ws, size_t ws_size,
                              hipStream_t stream)
{
  const float* bids = (const float*)d_in[0];
  const float* aw0 = (const float*)d_in[1];  const float* ab0 = (const float*)d_in[2];
  const float* aw1 = (const float*)d_in[3];  const float* ab1 = (const float*)d_in[4];
  const float* aw2 = (const float*)d_in[5];  const float* ab2 = (const float*)d_in[6];
  const float* aw3 = (const float*)d_in[7];  const float* ab3 = (const float*)d_in[8];
  const float* pw0 = (const float*)d_in[9];  const float* pb0 = (const float*)d_in[10];
  const float* pw1 = (const float*)d_in[11]; const float* pb1 = (const float*)d_in[12];
  const float* pw2 = (const float*)d_in[13]; const float* pb2 = (const float*)d_in[14];
  const float* pw3 = (const float*)d_in[15]; const float* pb3 = (const float*)d_in[16];

  // f16 transposed/split weights in workspace (no d_out aliasing — fused kernel
  // writes payments while other blocks still read WT)
  _Float16* WT = (_Float16*)d_ws;

  // nshift = log2(N) where W is K x N (row-major src); dst is N x K (transposed)
  PrepJobs js;
  js.j[0] = { aw0, WT+O_AW0H, nullptr,    7, 32768 };  // 256x128
  js.j[1] = { aw1, WT+O_AW1H, WT+O_AW1L,  7, 16384 };  // 128x128
  js.j[2] = { aw2, WT+O_AW2H, WT+O_AW2L,  7, 16384 };  // 128x128
  js.j[3] = { aw3, WT+O_AW3H, WT+O_AW3L,  8, 32768 };  // 128x256
  js.j[4] = { pw0, WT+O_PW0H, nullptr,    7, 32768 };  // 256x128
  js.j[5] = { pw1, WT+O_PW1H, nullptr,    7, 16384 };  // 128x128
  js.j[6] = { pw2, WT+O_PW2H, nullptr,    7, 16384 };  // 128x128
  js.j[7] = { pw3, WT+O_PW3H, nullptr,    4, 2048  };  // 128x16

  prep_kernel<<<dim3(128,8), 256, 0, stream>>>(js);
  fused_kernel<<<dim3(NB/16), 64, 0, stream>>>(bids, WT, ab0,ab1,ab2,ab3,
                                               pb0,pb1,pb2,pb3, (float*)d_out);
}

// Round 5
// 199.680 us; speedup vs baseline: 1.3254x; 1.1818x over previous
//
#include <hip/hip_runtime.h>

#define NB 32768

typedef _Float16 half8 __attribute__((ext_vector_type(8)));
typedef float floatx4 __attribute__((ext_vector_type(4)));
typedef float floatx2 __attribute__((ext_vector_type(2)));
typedef unsigned int uint4v __attribute__((ext_vector_type(4)));

#define MFMA16(a,b,c) __builtin_amdgcn_mfma_f32_16x16x32_f16(a,b,c,0,0,0)

// ---------- fast math ----------
__device__ __forceinline__ float rcp_f(float x){ return __builtin_amdgcn_rcpf(x); }
__device__ __forceinline__ float exp2_f(float x){ return __builtin_amdgcn_exp2f(x); }
__device__ __forceinline__ float tanh_f(float x){
  float e = exp2_f(x * 2.8853900817779268f);     // e^(2x)
  return (e - 1.0f) * rcp_f(e + 1.0f);
}
__device__ __forceinline__ float sigmoid_f(float x){
  return rcp_f(1.0f + exp2_f(-1.4426950408889634f * x));
}

// packed f32 math (VOP3P)
__device__ __forceinline__ floatx2 pk_mul2(floatx2 a, floatx2 b){
  floatx2 d; asm("v_pk_mul_f32 %0, %1, %2" : "=v"(d) : "v"(a), "v"(b)); return d;
}
__device__ __forceinline__ floatx2 pk_fma2(floatx2 a, floatx2 b, floatx2 c){
  floatx2 d; asm("v_pk_fma_f32 %0, %1, %2, %3" : "=v"(d) : "v"(a), "v"(b), "v"(c)); return d;
}

// DPP quad butterflies: xor1 = quad_perm[1,0,3,2]=0xB1, xor2 = [2,3,0,1]=0x4E
template<int CTRL>
__device__ __forceinline__ float dpp_qp(float x){
  return __builtin_bit_cast(float, __builtin_amdgcn_update_dpp(0, __builtin_bit_cast(int,x), CTRL, 0xF, 0xF, true));
}
__device__ __forceinline__ float qadd2(float x){
  x += dpp_qp<0xB1>(x);
  x += dpp_qp<0x4E>(x);
  return x;
}
__device__ __forceinline__ float qmax2(float x){
  x = fmaxf(x, dpp_qp<0xB1>(x));
  x = fmaxf(x, dpp_qp<0x4E>(x));
  return x;
}

// ---------- f16 weight region offsets (in _Float16 units), lives in d_ws ----------
constexpr int O_AW0H = 0;        // 256x128
constexpr int O_AW1H = 32768;    // 128x128
constexpr int O_AW2H = 49152;
constexpr int O_AW3H = 65536;    // 128x256
constexpr int O_PW0H = 98304;
constexpr int O_PW1H = 131072;
constexpr int O_PW2H = 147456;
constexpr int O_PW3H = 163840;   // 128x16
constexpr int O_AW1L = 165888;
constexpr int O_AW2L = 182272;
constexpr int O_AW3L = 198656;

// ---------- weight prep: transpose + split f32 -> f16 hi/lo ----------
struct PrepJob { const float* src; _Float16* h; _Float16* l; int nshift; int total; };
struct PrepJobs { PrepJob j[8]; };

__global__ void prep_kernel(PrepJobs js){
  const PrepJob jb = js.j[blockIdx.y];
  const int idx = blockIdx.x*256 + threadIdx.x;
  if (idx >= jb.total) return;
  const int N = 1 << jb.nshift;
  const int n = idx & (N-1);           // fastest-varying -> coalesced src read
  const int k = idx >> jb.nshift;
  const int K = jb.total >> jb.nshift;
  float w = jb.src[idx];               // src[k*N + n] == src[idx]
  _Float16 h = (_Float16)w;
  jb.h[(long)n*K + k] = h;
  if (jb.l) jb.l[(long)n*K + k] = (_Float16)(w - (float)h);
}

// ---------- LDS activation layout: 32 rows x 128 cols of packed (hi|lo) u32 ----------
// 16B-chunk XOR swizzle by (row&7)
__device__ __forceinline__ int aaddr(int row, int col){
  int cc = (col >> 2) ^ (row & 7);
  return row*128 + (cc<<2) + (col & 3);
}

template<bool NEED_LO>
__device__ __forceinline__ void read_frag(const unsigned int* __restrict__ act,
    int row, int ks, int q, half8& ah, half8& al)
{
  const int s = row & 7;
  const int cc0 = ks*8 + q*2;
  uint4v c0 = *(const uint4v*)(act + row*128 + (((cc0  ) ^ s)<<2));
  uint4v c1 = *(const uint4v*)(act + row*128 + (((cc0+1) ^ s)<<2));
  uint4v h;
  h.x = (c0.x & 0xffffu) | (c0.y << 16);
  h.y = (c0.z & 0xffffu) | (c0.w << 16);
  h.z = (c1.x & 0xffffu) | (c1.y << 16);
  h.w = (c1.z & 0xffffu) | (c1.w << 16);
  ah = __builtin_bit_cast(half8, h);
  if constexpr (NEED_LO){
    uint4v g;
    g.x = (c0.x >> 16) | (c0.y & 0xffff0000u);
    g.y = (c0.z >> 16) | (c0.w & 0xffff0000u);
    g.z = (c1.x >> 16) | (c1.y & 0xffff0000u);
    g.w = (c1.z >> 16) | (c1.w & 0xffff0000u);
    al = __builtin_bit_cast(half8, g);
  }
}

__device__ __forceinline__ unsigned int pack_act(float v){
  _Float16 h = (_Float16)v;
  _Float16 lo = (_Float16)(v - (float)h);
  return (unsigned int)__builtin_bit_cast(unsigned short, h)
       | ((unsigned int)__builtin_bit_cast(unsigned short, lo) << 16);
}
__device__ __forceinline__ unsigned int pack_act_hi(float v){
  return (unsigned int)__builtin_bit_cast(unsigned short, (_Float16)v);
}

// ---------- load one weight tile's fragments into a register stage ----------
template<int KS, bool LO>
__device__ __forceinline__ void load_tile(
    const _Float16* __restrict__ Wh, const _Float16* __restrict__ Wl,
    int K, int nt, int l15, int q, half8* bh, half8* bl)
{
  const _Float16* bp = Wh + (nt*16 + l15)*K + q*8;
#pragma unroll
  for (int ks=0; ks<KS; ++ks) bh[ks] = *(const half8*)(bp + ks*32);
  if constexpr (LO){
    const _Float16* blp = Wl + (nt*16 + l15)*K + q*8;
#pragma unroll
    for (int ks=0; ks<KS; ++ks) bl[ks] = *(const half8*)(blp + ks*32);
  }
}

// ---------- DUAL m-tile MFMA stream: each loaded B-frag feeds 2 MFMAs ----------
// Per tile-slot: [issue loads nt+RING-1] -> [MFMAs for both m-tiles, 4 acc
// chains] -> [epi(nt) VALU for both m-tiles]. 2x arithmetic intensity per load.
template<int KS, int PASSES, int NT, int RING, typename EPI>
__device__ __forceinline__ void mfma_stream2(
    const half8* Ah0, const half8* Al0,
    const half8* Ah1, const half8* Al1,
    const _Float16* __restrict__ Wh, const _Float16* __restrict__ Wl,
    int K, int l15, int q, EPI&& epi)
{
  half8 Bh[RING][KS], Bl[RING][KS];
  load_tile<KS,PASSES==3>(Wh, Wl, K, 0, l15, q, Bh[0], Bl[0]);
  if constexpr (RING > 2){
    if constexpr (NT > 1)
      load_tile<KS,PASSES==3>(Wh, Wl, K, 1, l15, q, Bh[1], Bl[1]);
  }
#pragma unroll
  for (int nt=0; nt<NT; ++nt){
    constexpr int PD = RING - 1;
    if (nt+PD < NT)
      load_tile<KS,PASSES==3>(Wh, Wl, K, nt+PD, l15, q, Bh[(nt+PD)%RING], Bl[(nt+PD)%RING]);
    floatx4 a0e=(floatx4)0.0f, a0o=(floatx4)0.0f;
    floatx4 a1e=(floatx4)0.0f, a1o=(floatx4)0.0f;
#pragma unroll
    for (int ks=0; ks<KS; ++ks){
      const half8 bh = Bh[nt%RING][ks];
      floatx4& c0 = (ks & 1) ? a0o : a0e;
      floatx4& c1 = (ks & 1) ? a1o : a1e;
      c0 = MFMA16(Ah0[ks], bh, c0);
      c1 = MFMA16(Ah1[ks], bh, c1);
      if constexpr (PASSES == 3){
        const half8 bl = Bl[nt%RING][ks];
        c0 = MFMA16(Al0[ks], bh, c0);
        c0 = MFMA16(Ah0[ks], bl, c0);
        c1 = MFMA16(Al1[ks], bh, c1);
        c1 = MFMA16(Ah1[ks], bl, c1);
      }
    }
    floatx4 acc0, acc1;
#pragma unroll
    for (int r=0; r<4; ++r){ acc0[r] = a0e[r] + a0o[r]; acc1[r] = a1e[r] + a1o[r]; }
    epi(nt, acc0, acc1);
  }
}

// ================= Fused kernel: MLPs + Sinkhorn + payments =================
// 64 threads = 1 wave per block, 32 rows/block (2 m-tiles). Zero barriers.
// LDS map: S[0..4096) = act_a (32x128 u32 hi|lo), S[4096..8192) = act_p,
//          S[0..8192) REUSED as aug f32 (32 rows x 256) after pL4 + aL4 pre-read.
//          S[8192..8704) = frac f32 (32x16).
// 1024 blocks -> 4 blocks/CU (LDS 4x34816B = 139KB). Intensity over occupancy.
__global__ __launch_bounds__(64, 2) void fused_kernel(
  const float* __restrict__ X, const _Float16* __restrict__ WT,
  const float* __restrict__ ab0, const float* __restrict__ ab1,
  const float* __restrict__ ab2, const float* __restrict__ ab3,
  const float* __restrict__ pb0, const float* __restrict__ pb1,
  const float* __restrict__ pb2, const float* __restrict__ pb3,
  float* __restrict__ out)
{
  __shared__ unsigned int S[32*256 + 512];   // 34816 B
  unsigned int* act_a = S;
  unsigned int* act_p = S + 4096;
  float* frac_l = (float*)(S + 8192);
  const int l = threadIdx.x, q = l>>4, l15 = l&15;
  const long rb = (long)blockIdx.x * 32;

  // per-tile epilogue maker: bias+tanh+pack both m-tiles
  auto epi_act = [&](unsigned int* act, const float* bias, bool lo){
    return [=](int nt, floatx4 acc0, floatx4 acc1){
      float bb = bias[nt*16 + l15];
#pragma unroll
      for (int r=0; r<4; ++r){
        float t0 = tanh_f(acc0[r] + bb);
        act[aaddr(q*4 + r, nt*16 + l15)] = lo ? pack_act(t0) : pack_act_hi(t0);
      }
#pragma unroll
      for (int r=0; r<4; ++r){
        float t1 = tanh_f(acc1[r] + bb);
        act[aaddr(16 + q*4 + r, nt*16 + l15)] = lo ? pack_act(t1) : pack_act_hi(t1);
      }
    };
  };

  // ---- L1 of both nets: X frags for both m-tiles (K=256) ----
  {
    half8 Xf0[8], Xf1[8];
#pragma unroll
    for (int mt=0; mt<2; ++mt){
      float4 xa[8], xb[8];
#pragma unroll
      for (int ks=0; ks<8; ++ks){
        const float* xp = X + (rb + mt*16 + l15)*256 + ks*32 + q*8;
        xa[ks] = *(const float4*)(xp);
        xb[ks] = *(const float4*)(xp + 4);
      }
      half8* Xf = mt ? Xf1 : Xf0;
#pragma unroll
      for (int ks=0; ks<8; ++ks){
        half8 h;
        h[0]=(_Float16)xa[ks].x; h[1]=(_Float16)xa[ks].y; h[2]=(_Float16)xa[ks].z; h[3]=(_Float16)xa[ks].w;
        h[4]=(_Float16)xb[ks].x; h[5]=(_Float16)xb[ks].y; h[6]=(_Float16)xb[ks].z; h[7]=(_Float16)xb[ks].w;
        Xf[ks] = h;
      }
    }
    mfma_stream2<8,1,8,2>(Xf0, Xf0, Xf1, Xf1, WT+O_AW0H, WT+O_AW0H, 256, l15, q,
                          epi_act(act_a, ab0, true));
    mfma_stream2<8,1,8,2>(Xf0, Xf0, Xf1, Xf1, WT+O_PW0H, WT+O_PW0H, 256, l15, q,
                          epi_act(act_p, pb0, false));
  }

  // ---- hidden layers: a (3-pass hi/lo), p (1-pass) ----
  {
    half8 Ah0[4], Al0[4], Ah1[4], Al1[4];
#pragma unroll
    for (int ks=0; ks<4; ++ks){
      read_frag<true>(act_a, l15,      ks, q, Ah0[ks], Al0[ks]);
      read_frag<true>(act_a, 16 + l15, ks, q, Ah1[ks], Al1[ks]);
    }
    mfma_stream2<4,3,8,2>(Ah0, Al0, Ah1, Al1, WT+O_AW1H, WT+O_AW1L, 128, l15, q,
                          epi_act(act_a, ab1, true));
  }
  {
    half8 Ph0[4], Ph1[4], du;
#pragma unroll
    for (int ks=0; ks<4; ++ks){
      read_frag<false>(act_p, l15,      ks, q, Ph0[ks], du);
      read_frag<false>(act_p, 16 + l15, ks, q, Ph1[ks], du);
    }
    mfma_stream2<4,1,8,3>(Ph0, Ph0, Ph1, Ph1, WT+O_PW1H, WT+O_PW1H, 128, l15, q,
                          epi_act(act_p, pb1, false));
  }
  {
    half8 Ah0[4], Al0[4], Ah1[4], Al1[4];
#pragma unroll
    for (int ks=0; ks<4; ++ks){
      read_frag<true>(act_a, l15,      ks, q, Ah0[ks], Al0[ks]);
      read_frag<true>(act_a, 16 + l15, ks, q, Ah1[ks], Al1[ks]);
    }
    mfma_stream2<4,3,8,2>(Ah0, Al0, Ah1, Al1, WT+O_AW2H, WT+O_AW2L, 128, l15, q,
                          epi_act(act_a, ab2, true));
  }
  {
    half8 Ph0[4], Ph1[4], du;
#pragma unroll
    for (int ks=0; ks<4; ++ks){
      read_frag<false>(act_p, l15,      ks, q, Ph0[ks], du);
      read_frag<false>(act_p, 16 + l15, ks, q, Ph1[ks], du);
    }
    mfma_stream2<4,1,8,3>(Ph0, Ph0, Ph1, Ph1, WT+O_PW2H, WT+O_PW2H, 128, l15, q,
                          epi_act(act_p, pb2, false));
  }

  // ---- p-net L4 -> frac (sigmoid) to LDS — MUST precede aL4's aug overlay ----
  {
    half8 Ph0[4], Ph1[4], du;
#pragma unroll
    for (int ks=0; ks<4; ++ks){
      read_frag<false>(act_p, l15,      ks, q, Ph0[ks], du);
      read_frag<false>(act_p, 16 + l15, ks, q, Ph1[ks], du);
    }
    mfma_stream2<4,1,1,2>(Ph0, Ph0, Ph1, Ph1, WT+O_PW3H, WT+O_PW3H, 128, l15, q,
      [&](int, floatx4 acc0, floatx4 acc1){
        float bb = pb3[l15];
#pragma unroll
        for (int r=0; r<4; ++r){
          frac_l[(q*4+r)*16 + l15]      = sigmoid_f(acc0[r] + bb);
          frac_l[(16+q*4+r)*16 + l15]   = sigmoid_f(acc1[r] + bb);
        }
      });
  }
  // ---- a-net L4 -> aug (f32) into LDS overlay; act_a fully pre-read to regs ----
  {
    half8 Ah0[4], Al0[4], Ah1[4], Al1[4];
#pragma unroll
    for (int ks=0; ks<4; ++ks){
      read_frag<true>(act_a, l15,      ks, q, Ah0[ks], Al0[ks]);
      read_frag<true>(act_a, 16 + l15, ks, q, Ah1[ks], Al1[ks]);
    }
    float* augl = (float*)S;
#pragma unroll
    for (int hf=0; hf<2; ++hf){
      const int ncol0 = hf*128;
      mfma_stream2<4,3,8,2>(Ah0, Al0, Ah1, Al1,
                            WT+O_AW3H + hf*128*128, WT+O_AW3L + hf*128*128,
                            128, l15, q,
        [&](int nt, floatx4 acc0, floatx4 acc1){
          float bb = ab3[ncol0 + nt*16 + l15];
#pragma unroll
          for (int r=0; r<4; ++r){
            augl[(q*4+r)*256 + ncol0 + nt*16 + l15]      = acc0[r] + bb;
            augl[(16+q*4+r)*256 + ncol0 + nt*16 + l15]   = acc1[r] + bb;
          }
        });
    }
  }

  // ================= Sinkhorn + payments: two sequential 16-element passes ====
  // Lane owns 4 columns (4c..4c+3) of element eL = mt*16 + (l>>2).
  const int c = l & 3;
  const float Ssc = 14.426950408889634f; // (1/EPS)/ln2 : logits in exp2 units
  const float cmask = (c == 3) ? 1.0f : 0.0f;

#pragma unroll 1
  for (int mt=0; mt<2; ++mt){
    const int eL = mt*16 + (l >> 2);
    const long e = rb + eL;

    floatx2 Kp[4][8];   // owned columns, rows (2k, 2k+1)
    floatx2 KPp[8];     // pad column 16 (lane 3 only; zero elsewhere), row-pairs

    const float* ap = (const float*)S + eL*256 + 4*c;
#pragma unroll
    for (int k=0;k<8;++k){
      float4 va = *(const float4*)(ap + (2*k  )*16);
      float4 vb = *(const float4*)(ap + (2*k+1)*16);
      Kp[0][k] = (floatx2){va.x*Ssc, vb.x*Ssc};
      Kp[1][k] = (floatx2){va.y*Ssc, vb.y*Ssc};
      Kp[2][k] = (floatx2){va.z*Ssc, vb.z*Ssc};
      Kp[3][k] = (floatx2){va.w*Ssc, vb.w*Ssc};
    }

    // max-subtract + exponentiate (row-wise, across the 4 lanes + pad col 0)
#pragma unroll
    for (int k=0;k<8;++k){
      float m0 = fmaxf(fmaxf(Kp[0][k].x,Kp[1][k].x), fmaxf(Kp[2][k].x,Kp[3][k].x));
      m0 = qmax2(fmaxf(m0, 0.0f));
      float m1 = fmaxf(fmaxf(Kp[0][k].y,Kp[1][k].y), fmaxf(Kp[2][k].y,Kp[3][k].y));
      m1 = qmax2(fmaxf(m1, 0.0f));
      Kp[0][k] = (floatx2){exp2_f(Kp[0][k].x-m0), exp2_f(Kp[0][k].y-m1)};
      Kp[1][k] = (floatx2){exp2_f(Kp[1][k].x-m0), exp2_f(Kp[1][k].y-m1)};
      Kp[2][k] = (floatx2){exp2_f(Kp[2][k].x-m0), exp2_f(Kp[2][k].y-m1)};
      Kp[3][k] = (floatx2){exp2_f(Kp[3][k].x-m0), exp2_f(Kp[3][k].y-m1)};
      KPp[k]   = (floatx2){cmask*exp2_f(-m0), cmask*exp2_f(-m1)};
    }
    // row 16: logits all 0, row max = 0 -> K entries exactly 1 (pad col: cmask)

    float vj0=1.f, vj1=1.f, vj2=1.f, vj3=1.f;
    float v16 = cmask;
    floatx2 u2[8];
    float u16;

    for (int r=0;r<40;++r){
      floatx2 b0=(floatx2){vj0,vj0}, b1=(floatx2){vj1,vj1};
      floatx2 b2=(floatx2){vj2,vj2}, b3=(floatx2){vj3,vj3};
      floatx2 b16=(floatx2){v16,v16};
      // ---- row normalization: u_i = 1 / sum_j K_ij v_j ----
#pragma unroll
      for (int k=0;k<8;++k){
        floatx2 pp = pk_mul2(Kp[0][k], b0);
        pp = pk_fma2(Kp[1][k], b1, pp);
        pp = pk_fma2(Kp[2][k], b2, pp);
        pp = pk_fma2(Kp[3][k], b3, pp);
        pp = pk_fma2(KPp[k], b16, pp);
        float px = qadd2(pp.x);
        float py = qadd2(pp.y);
        u2[k] = (floatx2){rcp_f(px), rcp_f(py)};
      }
      {
        // row 16: K == 1 across real cols, cmask on pad col; a_16 = I = 16
        float p16 = (vj0+vj1) + (vj2+vj3) + cmask*v16;
        p16 = qadd2(p16);
        u16 = 16.0f * rcp_f(p16);
      }
      // ---- column normalization: v_j = 1 / sum_i K_ij u_i ----
      floatx2 t0p = pk_mul2(Kp[0][0], u2[0]);
      floatx2 t1p = pk_mul2(Kp[1][0], u2[0]);
      floatx2 t2p = pk_mul2(Kp[2][0], u2[0]);
      floatx2 t3p = pk_mul2(Kp[3][0], u2[0]);
      floatx2 tPp = pk_mul2(KPp[0],   u2[0]);
#pragma unroll
      for (int k=1;k<8;++k){
        t0p = pk_fma2(Kp[0][k], u2[k], t0p);
        t1p = pk_fma2(Kp[1][k], u2[k], t1p);
        t2p = pk_fma2(Kp[2][k], u2[k], t2p);
        t3p = pk_fma2(Kp[3][k], u2[k], t3p);
        tPp = pk_fma2(KPp[k],   u2[k], tPp);
      }
      float t0 = t0p.x + t0p.y + u16;        // row-16 K == 1
      float t1 = t1p.x + t1p.y + u16;
      float t2 = t2p.x + t2p.y + u16;
      float t3 = t3p.x + t3p.y + u16;
      float t16 = tPp.x + tPp.y + cmask*u16;
      vj0 = rcp_f(t0); vj1 = rcp_f(t1); vj2 = rcp_f(t2); vj3 = rcp_f(t3);
      v16 = cmask * 16.0f * rcp_f(t16 + 1e-30f + (1.0f - cmask));  // b_16 = A = 16; NaN-guard off-lane
    }

    // ---- allocs = u_i K_ij v_j (write) + payments dot fused (reuse w) ----
    float* op = out + e*256 + 4*c;
    const float* bpx = X + e*256 + 4*c;
    float pv0=0.f, pv1=0.f, pv2=0.f, pv3=0.f;
#pragma unroll
    for (int k=0;k<8;++k){
#pragma unroll
      for (int h=0;h<2;++h){
        const int i = 2*k + h;
        const float uu = h ? u2[k].y : u2[k].x;
        const float K0 = h ? Kp[0][k].y : Kp[0][k].x;
        const float K1 = h ? Kp[1][k].y : Kp[1][k].x;
        const float K2 = h ? Kp[2][k].y : Kp[2][k].x;
        const float K3 = h ? Kp[3][k].y : Kp[3][k].x;
        float4 w;
        w.x = uu*K0*vj0;
        w.y = uu*K1*vj1;
        w.z = uu*K2*vj2;
        w.w = uu*K3*vj3;
        *(float4*)(op + i*16) = w;
        float4 bb = *(const float4*)(bpx + i*16);
        float s = w.x*bb.x + w.y*bb.y + w.z*bb.z + w.w*bb.w;
        s = qadd2(s);
        if ((i>>2) == c){
          const int rr = i & 3;
          if      (rr==0) pv0 = s;
          else if (rr==1) pv1 = s;
          else if (rr==2) pv2 = s;
          else            pv3 = s;
        }
      }
    }
    const float4 fr = *(const float4*)(frac_l + eL*16 + 4*c);
    float4 pvv;
    pvv.x = pv0*fr.x; pvv.y = pv1*fr.y; pvv.z = pv2*fr.z; pvv.w = pv3*fr.w;
    *(float4*)(out + (size_t)NB*256 + e*16 + 4*c) = pvv;
  }
}

// ================= launch =================
extern "C" void kernel_launch(void* const* d_in, const int* in_sizes, int n_in,
                              void* d_out, int out_size, void* d_ws, size_t ws_size,
                              hipStream_t stream)
{
  const float* bids = (const float*)d_in[0];
  const float* aw0 = (const float*)d_in[1];  const float* ab0 = (const float*)d_in[2];
  const float* aw1 = (const float*)d_in[3];  const float* ab1 = (const float*)d_in[4];
  const float* aw2 = (const float*)d_in[5];  const float* ab2 = (const float*)d_in[6];
  const float* aw3 = (const float*)d_in[7];  const float* ab3 = (const float*)d_in[8];
  const float* pw0 = (const float*)d_in[9];  const float* pb0 = (const float*)d_in[10];
  const float* pw1 = (const float*)d_in[11]; const float* pb1 = (const float*)d_in[12];
  const float* pw2 = (const float*)d_in[13]; const float* pb2 = (const float*)d_in[14];
  const float* pw3 = (const float*)d_in[15]; const float* pb3 = (const float*)d_in[16];

  _Float16* WT = (_Float16*)d_ws;

  // nshift = log2(N) where W is K x N (row-major src); dst is N x K (transposed)
  PrepJobs js;
  js.j[0] = { aw0, WT+O_AW0H, nullptr,    7, 32768 };  // 256x128
  js.j[1] = { aw1, WT+O_AW1H, WT+O_AW1L,  7, 16384 };  // 128x128
  js.j[2] = { aw2, WT+O_AW2H, WT+O_AW2L,  7, 16384 };  // 128x128
  js.j[3] = { aw3, WT+O_AW3H, WT+O_AW3L,  8, 32768 };  // 128x256
  js.j[4] = { pw0, WT+O_PW0H, nullptr,    7, 32768 };  // 256x128
  js.j[5] = { pw1, WT+O_PW1H, nullptr,    7, 16384 };  // 128x128
  js.j[6] = { pw2, WT+O_PW2H, nullptr,    7, 16384 };  // 128x128
  js.j[7] = { pw3, WT+O_PW3H, nullptr,    4, 2048  };  // 128x16

  prep_kernel<<<dim3(128,8), 256, 0, stream>>>(js);
  fused_kernel<<<dim3(NB/32), 64, 0, stream>>>(bids, WT, ab0,ab1,ab2,ab3,
                                               pb0,pb1,pb2,pb3, (float*)d_out);
}